// Round 2
// baseline (8423.800 us; speedup 1.0000x reference)
//
#include <hip/hip_runtime.h>
#include <hip/hip_bf16.h>
#include <math.h>

// Problem constants (Encoder_24816321036413)
#define B_   16
#define L_   1024
#define BL_  16384      // B_*L_
#define DX_  2
#define DH_  512
#define DFF_ 2048
#define NL_  3
#define M_   8
#define DK_  64
#define FFCH_ 2048      // FF row-chunk (keeps ws < 160 MB)

// ---------------------------------------------------------------------------
// h[bl][e] = x[bl][0]*Wh[e][0] + x[bl][1]*Wh[e][1] + bh[e]
__global__ __launch_bounds__(256) void embed_kernel(
    const float* __restrict__ x, const float* __restrict__ Wh,
    const float* __restrict__ bh, float* __restrict__ h)
{
    int idx = blockIdx.x * 256 + threadIdx.x;   // BL_*DH_ threads
    int bl  = idx >> 9;
    int e   = idx & 511;
    float x0 = x[bl * 2 + 0], x1 = x[bl * 2 + 1];
    h[idx] = fmaf(x0, Wh[e * 2 + 0], fmaf(x1, Wh[e * 2 + 1], bh[e]));
}

// ---------------------------------------------------------------------------
// C[M x N] = A[M x K] * B[N x K]^T (+bias, +relu).  flags: bit0 bias, bit1 relu
// 64x64 tile, BK=16, 256 threads, 4x4 microtile. LDS stored k-major with +4 pad.
__global__ __launch_bounds__(256) void gemm_nt_kernel(
    const float* __restrict__ A, const float* __restrict__ Bm,
    const float* __restrict__ bias, float* __restrict__ C,
    int M, int N, int K, int flags)
{
    __shared__ float As[16][68];   // [k][row]
    __shared__ float Bs[16][68];

    int tid = threadIdx.x;
    int bm0 = blockIdx.y * 64;
    int bn0 = blockIdx.x * 64;
    int lr  = tid >> 2;            // 0..63 load row
    int lc  = (tid & 3) << 2;      // 0,4,8,12 load col (float4)
    int ty  = tid >> 4;            // 0..15
    int tx  = tid & 15;            // 0..15

    const float* Ap = A  + (size_t)(bm0 + lr) * K + lc;
    const float* Bp = Bm + (size_t)(bn0 + lr) * K + lc;

    float4 av = *(const float4*)Ap;    // prefetch tile 0
    float4 bv = *(const float4*)Bp;

    float acc[4][4] = {};

    for (int k0 = 0; k0 < K; k0 += 16) {
        __syncthreads();
        As[lc + 0][lr] = av.x; As[lc + 1][lr] = av.y;
        As[lc + 2][lr] = av.z; As[lc + 3][lr] = av.w;
        Bs[lc + 0][lr] = bv.x; Bs[lc + 1][lr] = bv.y;
        Bs[lc + 2][lr] = bv.z; Bs[lc + 3][lr] = bv.w;
        __syncthreads();
        if (k0 + 16 < K) {                  // reg-staged prefetch of next tile
            av = *(const float4*)(Ap + k0 + 16);
            bv = *(const float4*)(Bp + k0 + 16);
        }
        #pragma unroll
        for (int kk = 0; kk < 16; ++kk) {
            float4 a4 = *(const float4*)&As[kk][ty << 2];
            float4 b4 = *(const float4*)&Bs[kk][tx << 2];
            float ar[4] = {a4.x, a4.y, a4.z, a4.w};
            float br[4] = {b4.x, b4.y, b4.z, b4.w};
            #pragma unroll
            for (int i = 0; i < 4; ++i)
                #pragma unroll
                for (int j = 0; j < 4; ++j)
                    acc[i][j] = fmaf(ar[i], br[j], acc[i][j]);
        }
    }

    bool hasb = flags & 1;
    bool relu = flags & 2;
    float bj[4] = {0.f, 0.f, 0.f, 0.f};
    if (hasb) {
        float4 bb = *(const float4*)&bias[bn0 + (tx << 2)];
        bj[0] = bb.x; bj[1] = bb.y; bj[2] = bb.z; bj[3] = bb.w;
    }
    #pragma unroll
    for (int i = 0; i < 4; ++i) {
        float4 o;
        o.x = acc[i][0] + bj[0];
        o.y = acc[i][1] + bj[1];
        o.z = acc[i][2] + bj[2];
        o.w = acc[i][3] + bj[3];
        if (relu) {
            o.x = fmaxf(o.x, 0.f); o.y = fmaxf(o.y, 0.f);
            o.z = fmaxf(o.z, 0.f); o.w = fmaxf(o.w, 0.f);
        }
        *(float4*)&C[(size_t)(bm0 + (ty << 2) + i) * N + bn0 + (tx << 2)] = o;
    }
}

// ---------------------------------------------------------------------------
// Repack Wo[n]: [M_][DH_][DK_] (m,d,v) -> wr[DH_][M_*DK_] : wr[d][m*64+v]
__global__ __launch_bounds__(256) void repack_wo_kernel(
    const float* __restrict__ Wo_n, float* __restrict__ wr)
{
    int idx = blockIdx.x * 256 + threadIdx.x;   // DH_*DH_
    int d = idx >> 9, mv = idx & 511;
    int mm = mv >> 6, vv = mv & 63;
    wr[idx] = Wo_n[((size_t)mm * DH_ + d) * DK_ + vv];
}

// ---------------------------------------------------------------------------
// Flash-style attention, one thread per q row, no score materialization.
// q/k/v/t layout: [b*L_ + l][512] with head m occupying cols m*64..m*64+63.
// Softmax without max-subtraction: |scores| <~ 16 here, exp() safely in fp32 range.
__global__ __launch_bounds__(256) void attn_kernel(
    const float* __restrict__ q, const float* __restrict__ k,
    const float* __restrict__ v, float* __restrict__ t)
{
    __shared__ float Ks[64][68];   // +4 pad: write banks 2-way only (free)
    __shared__ float Vs[64][68];

    int b = blockIdx.z, m = blockIdx.y;
    int qrow = blockIdx.x * 256 + threadIdx.x;
    size_t base = ((size_t)b * L_) * DH_ + m * DK_;

    const float* qp = q + base + (size_t)qrow * DH_;
    float qr[64];
    #pragma unroll
    for (int i = 0; i < 16; ++i) {
        float4 u = *(const float4*)&qp[i * 4];
        qr[4*i+0] = u.x; qr[4*i+1] = u.y; qr[4*i+2] = u.z; qr[4*i+3] = u.w;
    }
    float o[64];
    #pragma unroll
    for (int i = 0; i < 64; ++i) o[i] = 0.f;
    float den = 0.f;

    int lr  = threadIdx.x >> 2;          // 0..63
    int lc0 = (threadIdx.x & 3) << 4;    // 0,16,32,48

    for (int j0 = 0; j0 < L_; j0 += 64) {
        __syncthreads();
        const float* kp = k + base + (size_t)(j0 + lr) * DH_ + lc0;
        const float* vp = v + base + (size_t)(j0 + lr) * DH_ + lc0;
        #pragma unroll
        for (int u2 = 0; u2 < 4; ++u2) {
            *(float4*)&Ks[lr][lc0 + u2 * 4] = *(const float4*)&kp[u2 * 4];
            *(float4*)&Vs[lr][lc0 + u2 * 4] = *(const float4*)&vp[u2 * 4];
        }
        __syncthreads();
        #pragma unroll 2
        for (int j = 0; j < 64; ++j) {
            float s0 = 0.f, s1 = 0.f, s2 = 0.f, s3 = 0.f;
            #pragma unroll
            for (int i = 0; i < 16; ++i) {
                float4 k4 = *(const float4*)&Ks[j][i * 4];
                s0 = fmaf(qr[4*i+0], k4.x, s0);
                s1 = fmaf(qr[4*i+1], k4.y, s1);
                s2 = fmaf(qr[4*i+2], k4.z, s2);
                s3 = fmaf(qr[4*i+3], k4.w, s3);
            }
            float s = (s0 + s1) + (s2 + s3);
            float p = __expf(s * 0.125f);
            den += p;
            #pragma unroll
            for (int i = 0; i < 16; ++i) {
                float4 v4 = *(const float4*)&Vs[j][i * 4];
                o[4*i+0] = fmaf(p, v4.x, o[4*i+0]);
                o[4*i+1] = fmaf(p, v4.y, o[4*i+1]);
                o[4*i+2] = fmaf(p, v4.z, o[4*i+2]);
                o[4*i+3] = fmaf(p, v4.w, o[4*i+3]);
            }
        }
    }
    float inv = 1.f / den;
    float* tp = t + base + (size_t)qrow * DH_;
    #pragma unroll
    for (int i = 0; i < 16; ++i) {
        float4 u;
        u.x = o[4*i+0] * inv; u.y = o[4*i+1] * inv;
        u.z = o[4*i+2] * inv; u.w = o[4*i+3] * inv;
        *(float4*)&tp[i * 4] = u;
    }
}

// ---------------------------------------------------------------------------
// BatchNorm over (batch, feature) per position l: z = a + b (fused residual).
// stats[l] = mean, stats[L_+l] = rstd.  Biased variance, EPS=1e-5.
__global__ __launch_bounds__(256) void bn_stats_kernel(
    const float* __restrict__ a, const float* __restrict__ b,
    float* __restrict__ stats)
{
    int l = blockIdx.x, tid = threadIdx.x;
    float s = 0.f, s2 = 0.f;
    #pragma unroll
    for (int bb = 0; bb < B_; ++bb) {
        size_t off = ((size_t)bb * L_ + l) * DH_ + tid * 2;
        float2 va = *(const float2*)&a[off];
        float2 vb = *(const float2*)&b[off];
        float z0 = va.x + vb.x, z1 = va.y + vb.y;
        s += z0 + z1;
        s2 = fmaf(z0, z0, fmaf(z1, z1, s2));
    }
    #pragma unroll
    for (int off = 32; off > 0; off >>= 1) {
        s  += __shfl_down(s, off);
        s2 += __shfl_down(s2, off);
    }
    __shared__ float red[8];
    int w = tid >> 6;
    if ((tid & 63) == 0) { red[w] = s; red[4 + w] = s2; }
    __syncthreads();
    if (tid == 0) {
        float S  = red[0] + red[1] + red[2] + red[3];
        float S2 = red[4] + red[5] + red[6] + red[7];
        float mu  = S * (1.f / 8192.f);
        float var = S2 * (1.f / 8192.f) - mu * mu;
        stats[l]      = mu;
        stats[L_ + l] = rsqrtf(var + 1e-5f);
    }
}

// out[bl][d] = w[d] * ((a+b) - mean[l]) * rstd[l] + bias[d]
__global__ __launch_bounds__(256) void bn_apply_kernel(
    const float* __restrict__ a, const float* __restrict__ b,
    const float* __restrict__ stats, const float* __restrict__ w,
    const float* __restrict__ bias, float* __restrict__ out)
{
    int idx = blockIdx.x * 256 + threadIdx.x;   // BL_*DH_/4
    int bl = idx >> 7;
    int d4 = (idx & 127) << 2;
    int l  = bl & (L_ - 1);
    float mu = stats[l], rs = stats[L_ + l];
    size_t off = (size_t)bl * DH_ + d4;
    float4 va = *(const float4*)&a[off];
    float4 vb = *(const float4*)&b[off];
    float4 vw = *(const float4*)&w[d4];
    float4 vc = *(const float4*)&bias[d4];
    float4 o;
    o.x = fmaf(vw.x, ((va.x + vb.x) - mu) * rs, vc.x);
    o.y = fmaf(vw.y, ((va.y + vb.y) - mu) * rs, vc.y);
    o.z = fmaf(vw.z, ((va.z + vb.z) - mu) * rs, vc.z);
    o.w = fmaf(vw.w, ((va.w + vb.w) - mu) * rs, vc.w);
    *(float4*)&out[off] = o;
}

// ---------------------------------------------------------------------------
extern "C" void kernel_launch(void* const* d_in, const int* in_sizes, int n_in,
                              void* d_out, int out_size, void* d_ws, size_t ws_size,
                              hipStream_t stream)
{
    const float* x    = (const float*)d_in[0];
    const float* Wh   = (const float*)d_in[1];
    const float* bh   = (const float*)d_in[2];
    const float* Wq   = (const float*)d_in[3];
    const float* Wk   = (const float*)d_in[4];
    const float* Wv   = (const float*)d_in[5];
    const float* Wo   = (const float*)d_in[6];
    const float* wbn  = (const float*)d_in[7];
    const float* bbn  = (const float*)d_in[8];
    const float* Wff0 = (const float*)d_in[9];
    const float* bff0 = (const float*)d_in[10];
    const float* Wff1 = (const float*)d_in[11];
    const float* bff1 = (const float*)d_in[12];
    float* out = (float*)d_out;

    // Workspace layout (floats), total ~152 MB:
    //   h    [BL][DH]  32 MB   residual stream
    //   qb   [BL][DH]  32 MB   q        -> h_mha (Wo out)
    //   kb   [BL][DH]  32 MB   k        -> h_bn
    //   vb   [BL][DH]  32 MB   v        -> ff out
    //   ffm  [FFCH][DFF] 16 MB FF hidden chunk
    //   wr   [DH][DH]   1 MB   repacked Wo
    //   st   [2*L]      8 KB   BN stats
    // d_out doubles as attention-out t (dead before the final bn_apply write).
    float* ws = (float*)d_ws;
    const size_t SZ = (size_t)BL_ * DH_;          // 8,388,608
    float* h   = ws;
    float* qb  = h  + SZ;
    float* kb  = qb + SZ;
    float* vb  = kb + SZ;
    float* ffm = vb + SZ;                          // [FFCH_][DFF_]
    float* wr  = ffm + (size_t)FFCH_ * DFF_;
    float* st  = wr  + (size_t)DH_ * DH_;
    float* tb  = out;

    embed_kernel<<<BL_ * DH_ / 256, 256, 0, stream>>>(x, Wh, bh, h);

    dim3 g512(DH_ / 64, BL_ / 64);
    dim3 gff1(DFF_ / 64, FFCH_ / 64);
    dim3 gff2(DH_ / 64, FFCH_ / 64);
    dim3 gattn(L_ / 256, M_, B_);
    int gbn_apply = BL_ * DH_ / 4 / 256;

    for (int n = 0; n < NL_; ++n) {
        const float* Wq_n   = Wq   + (size_t)n * M_ * DK_ * DH_;
        const float* Wk_n   = Wk   + (size_t)n * M_ * DK_ * DH_;
        const float* Wv_n   = Wv   + (size_t)n * M_ * DK_ * DH_;
        const float* Wo_n   = Wo   + (size_t)n * M_ * DH_ * DK_;
        const float* wbn_n  = wbn  + (size_t)n * DH_;
        const float* bbn_n  = bbn  + (size_t)n * DH_;
        const float* Wff0_n = Wff0 + (size_t)n * DFF_ * DH_;
        const float* bff0_n = bff0 + (size_t)n * DFF_;
        const float* Wff1_n = Wff1 + (size_t)n * DH_ * DFF_;
        const float* bff1_n = bff1 + (size_t)n * DH_;

        // q,k,v = h @ W^T   (cols laid out (m, dk) = m*64+dk)
        gemm_nt_kernel<<<g512, 256, 0, stream>>>(h, Wq_n, nullptr, qb, BL_, DH_, DH_, 0);
        gemm_nt_kernel<<<g512, 256, 0, stream>>>(h, Wk_n, nullptr, kb, BL_, DH_, DH_, 0);
        gemm_nt_kernel<<<g512, 256, 0, stream>>>(h, Wv_n, nullptr, vb, BL_, DH_, DH_, 0);
        // t = softmax(q k^T / 8) v     per (b, m)
        attn_kernel<<<gattn, 256, 0, stream>>>(qb, kb, vb, tb);
        // h_mha = t @ Wo_repacked^T  (sum over heads)
        repack_wo_kernel<<<DH_ * DH_ / 256, 256, 0, stream>>>(Wo_n, wr);
        gemm_nt_kernel<<<g512, 256, 0, stream>>>(tb, wr, nullptr, qb, BL_, DH_, DH_, 0);
        // h_bn = w*BN(h + h_mha) + b
        bn_stats_kernel<<<L_, 256, 0, stream>>>(h, qb, st);
        bn_apply_kernel<<<gbn_apply, 256, 0, stream>>>(h, qb, st, wbn_n, bbn_n, kb);
        // ff = relu(h_bn @ Wff0^T + bff0) @ Wff1^T + bff1   (row-chunked)
        for (int r0 = 0; r0 < BL_; r0 += FFCH_) {
            gemm_nt_kernel<<<gff1, 256, 0, stream>>>(kb + (size_t)r0 * DH_, Wff0_n,
                                                     bff0_n, ffm, FFCH_, DFF_, DH_, 1 | 2);
            gemm_nt_kernel<<<gff2, 256, 0, stream>>>(ffm, Wff1_n, bff1_n,
                                                     vb + (size_t)r0 * DH_, FFCH_, DH_, DFF_, 1);
        }
        // h = w*BN(h_bn + ff) + b    (final layer -> d_out)
        bn_stats_kernel<<<L_, 256, 0, stream>>>(kb, vb, st);
        bn_apply_kernel<<<gbn_apply, 256, 0, stream>>>(kb, vb, st, wbn_n, bbn_n,
                                                       (n == NL_ - 1) ? out : h);
    }
}

// Round 3
// 4217.933 us; speedup vs baseline: 1.9971x; 1.9971x over previous
//
#include <hip/hip_runtime.h>
#include <hip/hip_bf16.h>
#include <math.h>

// Problem constants (Encoder_24816321036413)
#define B_   16
#define L_   1024
#define BL_  16384      // B_*L_
#define DH_  512
#define DFF_ 2048
#define NL_  3
#define M_   8
#define DK_  64
#define FFCH_ 8192      // FF row-chunk: FF1 gets 256 WGs (full machine), ffm stays 32 MB

typedef __attribute__((ext_vector_type(8))) short bf16x8;
typedef __attribute__((ext_vector_type(4))) float f32x4;
typedef __attribute__((ext_vector_type(4))) unsigned short us4;

__device__ __forceinline__ unsigned short f2b(float x) {
    __hip_bfloat16 h = __float2bfloat16(x);   // RNE
    return *(unsigned short*)&h;
}

// ---------------------------------------------------------------------------
// h[bl][e] (fp32 + bf16 copies)
__global__ __launch_bounds__(256) void embed_kernel(
    const float* __restrict__ x, const float* __restrict__ Wh,
    const float* __restrict__ bh, float* __restrict__ h,
    unsigned short* __restrict__ hb)
{
    int idx = blockIdx.x * 256 + threadIdx.x;
    int bl  = idx >> 9;
    int e   = idx & 511;
    float v = fmaf(x[bl * 2], Wh[e * 2], fmaf(x[bl * 2 + 1], Wh[e * 2 + 1], bh[e]));
    h[idx]  = v;
    hb[idx] = f2b(v);
}

// ---------------------------------------------------------------------------
// fp32 -> bf16, 4 elems/thread (n multiple of 1024)
__global__ __launch_bounds__(256) void cvt_f2b_kernel(
    const float* __restrict__ in, unsigned short* __restrict__ out)
{
    int i = (blockIdx.x * 256 + threadIdx.x) * 4;
    float4 v = *(const float4*)&in[i];
    us4 o;
    o.x = f2b(v.x); o.y = f2b(v.y); o.z = f2b(v.z); o.w = f2b(v.w);
    *(us4*)&out[i] = o;
}

// Repack+convert Wo[n]: [M_][DH_][DK_] (m,d,v) -> wr[d][m*64+v] bf16
__global__ __launch_bounds__(256) void repack_wo_kernel(
    const float* __restrict__ Wo_n, unsigned short* __restrict__ wr)
{
    int idx = blockIdx.x * 256 + threadIdx.x;   // DH_*DH_
    int d = idx >> 9, mv = idx & 511;
    int mm = mv >> 6, vv = mv & 63;
    wr[idx] = f2b(Wo_n[((size_t)mm * DH_ + d) * DK_ + vv]);
}

// ---------------------------------------------------------------------------
// MFMA bf16 GEMM-NT (m97 structure): C[M x N] = A[M x K] * B[N x K]^T.
// 128x128 tile, BK=32, 256 thr = 4 waves (2x2 of 64x64), 16x16x32 bf16 MFMA.
// Staging via global_load_lds width=16 (linear LDS, wave-uniform base + lane*16).
// flags: bit0 bias, bit1 relu.  Cf (fp32) and/or Cb (bf16) outputs, null-skipped.
__global__ __launch_bounds__(256) void gemm_bf16_kernel(
    const unsigned short* __restrict__ A, const unsigned short* __restrict__ Bm,
    const float* __restrict__ bias, float* __restrict__ Cf,
    unsigned short* __restrict__ Cb, int N, int K, int flags)
{
    __shared__ unsigned short As[128 * 32];   // row-major [128][32] bf16, 8 KB
    __shared__ unsigned short Bs[128 * 32];

    int tid  = threadIdx.x;
    int lane = tid & 63, wid = tid >> 6;
    int bm0 = blockIdx.y * 128, bn0 = blockIdx.x * 128;
    int wrow = (wid >> 1) * 64, wcol = (wid & 1) * 64;   // wave's 64x64 sub-tile
    int fr = lane & 15, fq = lane >> 4;

    f32x4 acc[4][4];
    #pragma unroll
    for (int i = 0; i < 4; ++i)
        #pragma unroll
        for (int j = 0; j < 4; ++j)
            acc[i][j] = (f32x4){0.f, 0.f, 0.f, 0.f};

    // 16B granule g: row = g>>2 (0..127), k-offset = (g&3)*8 elems.
    // call0: g = tid (rows 0..63), call1: g = 256+tid (rows 64..127).
    const unsigned short* a0 = A + (size_t)(bm0 +      (tid >> 2)) * K + (tid & 3) * 8;
    const unsigned short* a1 = A + (size_t)(bm0 + 64 + (tid >> 2)) * K + (tid & 3) * 8;
    const unsigned short* b0 = Bm + (size_t)(bn0 +      (tid >> 2)) * K + (tid & 3) * 8;
    const unsigned short* b1 = Bm + (size_t)(bn0 + 64 + (tid >> 2)) * K + (tid & 3) * 8;
    unsigned short* lA0 = As + wid * 512;          // wave-uniform LDS bases
    unsigned short* lA1 = As + 2048 + wid * 512;
    unsigned short* lB0 = Bs + wid * 512;
    unsigned short* lB1 = Bs + 2048 + wid * 512;

#define GLDS(g, l) __builtin_amdgcn_global_load_lds( \
        (const __attribute__((address_space(1))) unsigned int*)(const void*)(g), \
        (__attribute__((address_space(3))) unsigned int*)(void*)(l), 16, 0, 0)

    for (int k0 = 0; k0 < K; k0 += 32) {
        __syncthreads();                 // prev-iter ds_reads done before overwrite
        GLDS(a0 + k0, lA0);
        GLDS(a1 + k0, lA1);
        GLDS(b0 + k0, lB0);
        GLDS(b1 + k0, lB1);
        __syncthreads();                 // emits s_waitcnt vmcnt(0) before barrier

        bf16x8 af[4], bfr[4];
        #pragma unroll
        for (int i = 0; i < 4; ++i) {
            af[i]  = *(const bf16x8*)&As[(wrow + i * 16 + fr) * 32 + fq * 8];
            bfr[i] = *(const bf16x8*)&Bs[(wcol + i * 16 + fr) * 32 + fq * 8];
        }
        #pragma unroll
        for (int mi = 0; mi < 4; ++mi)
            #pragma unroll
            for (int ni = 0; ni < 4; ++ni)
                acc[mi][ni] = __builtin_amdgcn_mfma_f32_16x16x32_bf16(
                    af[mi], bfr[ni], acc[mi][ni], 0, 0, 0);
    }
#undef GLDS

    float bj[4] = {0.f, 0.f, 0.f, 0.f};
    if (flags & 1) {
        #pragma unroll
        for (int ni = 0; ni < 4; ++ni) bj[ni] = bias[bn0 + wcol + ni * 16 + fr];
    }
    bool relu = flags & 2;
    #pragma unroll
    for (int mi = 0; mi < 4; ++mi) {
        #pragma unroll
        for (int ni = 0; ni < 4; ++ni) {
            int col = bn0 + wcol + ni * 16 + fr;
            #pragma unroll
            for (int r = 0; r < 4; ++r) {
                int row = bm0 + wrow + mi * 16 + fq * 4 + r;   // C/D: col=lane&15, row=(lane>>4)*4+reg
                float v = acc[mi][ni][r] + bj[ni];
                if (relu) v = fmaxf(v, 0.f);
                if (Cf) Cf[(size_t)row * N + col] = v;
                if (Cb) Cb[(size_t)row * N + col] = f2b(v);
            }
        }
    }
}

// ---------------------------------------------------------------------------
// Flash-style fp32 attention over fused qkv buffer [BL][1536] (q|k|v slabs).
// Writes t fp32 (for later reuse) + bf16 copy (Wo GEMM A-operand).
__global__ __launch_bounds__(256) void attn_kernel(
    const float* __restrict__ qkv, float* __restrict__ t,
    unsigned short* __restrict__ tb)
{
    __shared__ float Ks[64][68];
    __shared__ float Vs[64][68];

    int b = blockIdx.z, m = blockIdx.y;
    int qrow = blockIdx.x * 256 + threadIdx.x;
    size_t rb = (size_t)b * L_ * 1536 + m * DK_;

    const float* qp = qkv + rb + (size_t)qrow * 1536;
    float qr[64];
    #pragma unroll
    for (int i = 0; i < 16; ++i) {
        float4 u = *(const float4*)&qp[i * 4];
        qr[4*i+0] = u.x; qr[4*i+1] = u.y; qr[4*i+2] = u.z; qr[4*i+3] = u.w;
    }
    float o[64];
    #pragma unroll
    for (int i = 0; i < 64; ++i) o[i] = 0.f;
    float den = 0.f;

    int lr  = threadIdx.x >> 2;
    int lc0 = (threadIdx.x & 3) << 4;

    for (int j0 = 0; j0 < L_; j0 += 64) {
        __syncthreads();
        const float* kp = qkv + rb + (size_t)(j0 + lr) * 1536 + 512 + lc0;
        const float* vp = qkv + rb + (size_t)(j0 + lr) * 1536 + 1024 + lc0;
        #pragma unroll
        for (int u2 = 0; u2 < 4; ++u2) {
            *(float4*)&Ks[lr][lc0 + u2 * 4] = *(const float4*)&kp[u2 * 4];
            *(float4*)&Vs[lr][lc0 + u2 * 4] = *(const float4*)&vp[u2 * 4];
        }
        __syncthreads();
        #pragma unroll 2
        for (int j = 0; j < 64; ++j) {
            float s0 = 0.f, s1 = 0.f, s2 = 0.f, s3 = 0.f;
            #pragma unroll
            for (int i = 0; i < 16; ++i) {
                float4 k4 = *(const float4*)&Ks[j][i * 4];
                s0 = fmaf(qr[4*i+0], k4.x, s0);
                s1 = fmaf(qr[4*i+1], k4.y, s1);
                s2 = fmaf(qr[4*i+2], k4.z, s2);
                s3 = fmaf(qr[4*i+3], k4.w, s3);
            }
            float s = (s0 + s1) + (s2 + s3);
            float p = __expf(s * 0.125f);
            den += p;
            #pragma unroll
            for (int i = 0; i < 16; ++i) {
                float4 v4 = *(const float4*)&Vs[j][i * 4];
                o[4*i+0] = fmaf(p, v4.x, o[4*i+0]);
                o[4*i+1] = fmaf(p, v4.y, o[4*i+1]);
                o[4*i+2] = fmaf(p, v4.z, o[4*i+2]);
                o[4*i+3] = fmaf(p, v4.w, o[4*i+3]);
            }
        }
    }
    float inv = 1.f / den;
    size_t ob = ((size_t)b * L_ + qrow) * DH_ + m * DK_;
    #pragma unroll
    for (int i = 0; i < 16; ++i) {
        float4 u;
        u.x = o[4*i+0] * inv; u.y = o[4*i+1] * inv;
        u.z = o[4*i+2] * inv; u.w = o[4*i+3] * inv;
        *(float4*)&t[ob + i * 4] = u;
        us4 ub;
        ub.x = f2b(u.x); ub.y = f2b(u.y); ub.z = f2b(u.z); ub.w = f2b(u.w);
        *(us4*)&tb[ob + i * 4] = ub;
    }
}

// ---------------------------------------------------------------------------
// BatchNorm per position l over (batch, feature); z = a + b (fused residual).
__global__ __launch_bounds__(256) void bn_stats_kernel(
    const float* __restrict__ a, const float* __restrict__ b,
    float* __restrict__ stats)
{
    int l = blockIdx.x, tid = threadIdx.x;
    float s = 0.f, s2 = 0.f;
    #pragma unroll
    for (int bb = 0; bb < B_; ++bb) {
        size_t off = ((size_t)bb * L_ + l) * DH_ + tid * 2;
        float2 va = *(const float2*)&a[off];
        float2 vb = *(const float2*)&b[off];
        float z0 = va.x + vb.x, z1 = va.y + vb.y;
        s += z0 + z1;
        s2 = fmaf(z0, z0, fmaf(z1, z1, s2));
    }
    #pragma unroll
    for (int off = 32; off > 0; off >>= 1) {
        s  += __shfl_down(s, off);
        s2 += __shfl_down(s2, off);
    }
    __shared__ float red[8];
    int w = tid >> 6;
    if ((tid & 63) == 0) { red[w] = s; red[4 + w] = s2; }
    __syncthreads();
    if (tid == 0) {
        float S  = red[0] + red[1] + red[2] + red[3];
        float S2 = red[4] + red[5] + red[6] + red[7];
        float mu  = S * (1.f / 8192.f);
        float var = S2 * (1.f / 8192.f) - mu * mu;
        stats[l]      = mu;
        stats[L_ + l] = rsqrtf(var + 1e-5f);
    }
}

// out = w*((a+b)-mu)*rstd + bias, fp32 (+ optional bf16 copy)
__global__ __launch_bounds__(256) void bn_apply_kernel(
    const float* __restrict__ a, const float* __restrict__ b,
    const float* __restrict__ stats, const float* __restrict__ w,
    const float* __restrict__ bias, float* __restrict__ out,
    unsigned short* __restrict__ outb)
{
    int idx = blockIdx.x * 256 + threadIdx.x;
    int bl = idx >> 7;
    int d4 = (idx & 127) << 2;
    int l  = bl & (L_ - 1);
    float mu = stats[l], rs = stats[L_ + l];
    size_t off = (size_t)bl * DH_ + d4;
    float4 va = *(const float4*)&a[off];
    float4 vb = *(const float4*)&b[off];
    float4 vw = *(const float4*)&w[d4];
    float4 vc = *(const float4*)&bias[d4];
    float4 o;
    o.x = fmaf(vw.x, ((va.x + vb.x) - mu) * rs, vc.x);
    o.y = fmaf(vw.y, ((va.y + vb.y) - mu) * rs, vc.y);
    o.z = fmaf(vw.z, ((va.z + vb.z) - mu) * rs, vc.z);
    o.w = fmaf(vw.w, ((va.w + vb.w) - mu) * rs, vc.w);
    *(float4*)&out[off] = o;
    if (outb) {
        us4 ub;
        ub.x = f2b(o.x); ub.y = f2b(o.y); ub.z = f2b(o.z); ub.w = f2b(o.w);
        *(us4*)&outb[off] = ub;
    }
}

// ---------------------------------------------------------------------------
extern "C" void kernel_launch(void* const* d_in, const int* in_sizes, int n_in,
                              void* d_out, int out_size, void* d_ws, size_t ws_size,
                              hipStream_t stream)
{
    const float* x    = (const float*)d_in[0];
    const float* Wh   = (const float*)d_in[1];
    const float* bh   = (const float*)d_in[2];
    const float* Wq   = (const float*)d_in[3];
    const float* Wk   = (const float*)d_in[4];
    const float* Wv   = (const float*)d_in[5];
    const float* Wo   = (const float*)d_in[6];
    const float* wbn  = (const float*)d_in[7];
    const float* bbn  = (const float*)d_in[8];
    const float* Wff0 = (const float*)d_in[9];
    const float* bff0 = (const float*)d_in[10];
    const float* Wff1 = (const float*)d_in[11];
    const float* bff1 = (const float*)d_in[12];
    float* out = (float*)d_out;

    // Workspace (~198 MB):
    //  fp32: h[BL][512] 32MB | qkv[BL][1536] 96MB (b0/b1/b2 = hmha/hbn/ff after attn)
    //        st[2L] 8KB
    //  bf16: hb 16MB | tbb (t / h_bn) 16MB | ffmb[FFCH][DFF] 32MB
    //        wqkvb[1536][512] | wob[512][512] | wff0b[2048][512] | wff1b[512][2048]
    float* ws = (float*)d_ws;
    const size_t SZ = (size_t)BL_ * DH_;          // 8,388,608
    float* h   = ws;
    float* qkv = h + SZ;
    float* st  = qkv + 3 * SZ;
    unsigned short* hb    = (unsigned short*)(st + 2048);
    unsigned short* tbb   = hb + SZ;
    unsigned short* ffmb  = tbb + SZ;                         // FFCH_*DFF_ = 16M
    unsigned short* wqkvb = ffmb + (size_t)FFCH_ * DFF_;
    unsigned short* wob   = wqkvb + 1536 * 512;
    unsigned short* wff0b = wob + 512 * 512;
    unsigned short* wff1b = wff0b + (size_t)DFF_ * DH_;
    float* b0 = qkv;            // h_mha
    float* b1 = qkv + SZ;       // h_bn
    float* b2 = qkv + 2 * SZ;   // ff out

    embed_kernel<<<BL_ * DH_ / 256, 256, 0, stream>>>(x, Wh, bh, h, hb);

    dim3 gqkv(1536 / 128, BL_ / 128);
    dim3 gwo(DH_ / 128, BL_ / 128);
    dim3 gff0(DFF_ / 128, FFCH_ / 128);
    dim3 gff1(DH_ / 128, FFCH_ / 128);
    dim3 gattn(L_ / 256, M_, B_);
    int gbn = BL_ * DH_ / 4 / 256;
    const int WSZ = DK_ * DH_ * M_;   // 262144, one Wq/Wk/Wv layer slab

    for (int n = 0; n < NL_; ++n) {
        const float* Wo_n   = Wo   + (size_t)n * M_ * DH_ * DK_;
        const float* wbn_n  = wbn  + (size_t)n * DH_;
        const float* bbn_n  = bbn  + (size_t)n * DH_;
        const float* bff0_n = bff0 + (size_t)n * DFF_;
        const float* bff1_n = bff1 + (size_t)n * DH_;

        // weight prep (bf16)
        cvt_f2b_kernel<<<WSZ / 1024, 256, 0, stream>>>(Wq + (size_t)n * WSZ, wqkvb);
        cvt_f2b_kernel<<<WSZ / 1024, 256, 0, stream>>>(Wk + (size_t)n * WSZ, wqkvb + WSZ);
        cvt_f2b_kernel<<<WSZ / 1024, 256, 0, stream>>>(Wv + (size_t)n * WSZ, wqkvb + 2 * WSZ);
        repack_wo_kernel<<<DH_ * DH_ / 256, 256, 0, stream>>>(Wo_n, wob);
        cvt_f2b_kernel<<<DFF_ * DH_ / 1024, 256, 0, stream>>>(Wff0 + (size_t)n * DFF_ * DH_, wff0b);
        cvt_f2b_kernel<<<DFF_ * DH_ / 1024, 256, 0, stream>>>(Wff1 + (size_t)n * DH_ * DFF_, wff1b);

        // qkv = hb @ wqkvb^T   [BL][1536] fp32
        gemm_bf16_kernel<<<gqkv, 256, 0, stream>>>(hb, wqkvb, nullptr, qkv, nullptr, 1536, DH_, 0);
        // t = softmax(q k^T / 8) v  -> d_out fp32 + tbb bf16
        attn_kernel<<<gattn, 256, 0, stream>>>(qkv, out, tbb);
        // h_mha = t @ wob^T -> b0 fp32
        gemm_bf16_kernel<<<gwo, 256, 0, stream>>>(tbb, wob, nullptr, b0, nullptr, DH_, DH_, 0);
        // h_bn = w*BN(h + h_mha) + b -> b1 fp32 + tbb bf16 (tbb dead, reuse)
        bn_stats_kernel<<<L_, 256, 0, stream>>>(h, b0, st);
        bn_apply_kernel<<<gbn, 256, 0, stream>>>(h, b0, st, wbn_n, bbn_n, b1, tbb);
        // ff = relu(h_bn @ Wff0^T + bff0) @ Wff1^T + bff1 -> b2 (row-chunked)
        for (int r0 = 0; r0 < BL_; r0 += FFCH_) {
            gemm_bf16_kernel<<<gff0, 256, 0, stream>>>(tbb + (size_t)r0 * DH_, wff0b,
                bff0_n, nullptr, ffmb, DFF_, DH_, 1 | 2);
            gemm_bf16_kernel<<<gff1, 256, 0, stream>>>(ffmb, wff1b,
                bff1_n, b2 + (size_t)r0 * DH_, nullptr, DH_, DFF_, 1);
        }
        // h = w*BN(h_bn + ff) + b   (final layer -> d_out, no bf16 copy)
        bn_stats_kernel<<<L_, 256, 0, stream>>>(b1, b2, st);
        bn_apply_kernel<<<gbn, 256, 0, stream>>>(b1, b2, st, wbn_n, bbn_n,
            (n == NL_ - 1) ? out : h, (n == NL_ - 1) ? nullptr : hb);
    }
}

// Round 4
// 1159.426 us; speedup vs baseline: 7.2655x; 3.6379x over previous
//
#include <hip/hip_runtime.h>
#include <hip/hip_bf16.h>
#include <math.h>

// Problem constants (Encoder_24816321036413)
#define B_   16
#define L_   1024
#define BL_  16384      // B_*L_
#define DH_  512
#define DFF_ 2048
#define NL_  3
#define M_   8
#define DK_  64
#define FFCH_ 8192

typedef __attribute__((ext_vector_type(8))) short bf16x8;
typedef __attribute__((ext_vector_type(4))) float f32x4;
typedef __attribute__((ext_vector_type(4))) unsigned short us4;

__device__ __forceinline__ unsigned short f2b(float x) {
    __hip_bfloat16 h = __float2bfloat16(x);   // RNE
    return *(unsigned short*)&h;
}

// ---------------------------------------------------------------------------
__global__ __launch_bounds__(256) void embed_kernel(
    const float* __restrict__ x, const float* __restrict__ Wh,
    const float* __restrict__ bh, float* __restrict__ h,
    unsigned short* __restrict__ hb)
{
    int idx = blockIdx.x * 256 + threadIdx.x;
    int bl  = idx >> 9;
    int e   = idx & 511;
    float v = fmaf(x[bl * 2], Wh[e * 2], fmaf(x[bl * 2 + 1], Wh[e * 2 + 1], bh[e]));
    h[idx]  = v;
    hb[idx] = f2b(v);
}

__global__ __launch_bounds__(256) void cvt_f2b_kernel(
    const float* __restrict__ in, unsigned short* __restrict__ out)
{
    int i = (blockIdx.x * 256 + threadIdx.x) * 4;
    float4 v = *(const float4*)&in[i];
    us4 o;
    o.x = f2b(v.x); o.y = f2b(v.y); o.z = f2b(v.z); o.w = f2b(v.w);
    *(us4*)&out[i] = o;
}

// Repack+convert Wo[n]: [M_][DH_][DK_] (m,d,v) -> wr[d][m*64+v] bf16
__global__ __launch_bounds__(256) void repack_wo_kernel(
    const float* __restrict__ Wo_n, unsigned short* __restrict__ wr)
{
    int idx = blockIdx.x * 256 + threadIdx.x;   // DH_*DH_
    int d = idx >> 9, mv = idx & 511;
    int mm = mv >> 6, vv = mv & 63;
    wr[idx] = f2b(Wo_n[((size_t)mm * DH_ + d) * DK_ + vv]);
}

// ---------------------------------------------------------------------------
// MFMA bf16 GEMM-NT: C[M x N] = A[M x K] * B[N x K]^T.
// 128x128 tile, BK=32, 4 waves, 16x16x32 MFMA, global_load_lds width=16.
// flags: bit0 bias, bit1 relu, bit2 qkv-mode (cols<1024 -> Cb row-major stride cn,
//        cols>=1024 -> vT[b,m][d][l] transposed bf16 scatter).
__global__ __launch_bounds__(256) void gemm_bf16_kernel(
    const unsigned short* __restrict__ A, const unsigned short* __restrict__ Bm,
    const float* __restrict__ bias, float* __restrict__ Cf,
    unsigned short* __restrict__ Cb, unsigned short* __restrict__ vT,
    int N, int K, int cn, int flags)
{
    __shared__ unsigned short As[128 * 32];
    __shared__ unsigned short Bs[128 * 32];

    int tid  = threadIdx.x;
    int lane = tid & 63, wid = tid >> 6;
    int bm0 = blockIdx.y * 128, bn0 = blockIdx.x * 128;
    int wrow = (wid >> 1) * 64, wcol = (wid & 1) * 64;
    int fr = lane & 15, fq = lane >> 4;

    f32x4 acc[4][4];
    #pragma unroll
    for (int i = 0; i < 4; ++i)
        #pragma unroll
        for (int j = 0; j < 4; ++j)
            acc[i][j] = (f32x4){0.f, 0.f, 0.f, 0.f};

    const unsigned short* a0 = A + (size_t)(bm0 +      (tid >> 2)) * K + (tid & 3) * 8;
    const unsigned short* a1 = A + (size_t)(bm0 + 64 + (tid >> 2)) * K + (tid & 3) * 8;
    const unsigned short* b0 = Bm + (size_t)(bn0 +      (tid >> 2)) * K + (tid & 3) * 8;
    const unsigned short* b1 = Bm + (size_t)(bn0 + 64 + (tid >> 2)) * K + (tid & 3) * 8;
    unsigned short* lA0 = As + wid * 512;
    unsigned short* lA1 = As + 2048 + wid * 512;
    unsigned short* lB0 = Bs + wid * 512;
    unsigned short* lB1 = Bs + 2048 + wid * 512;

#define GLDS(g, l) __builtin_amdgcn_global_load_lds( \
        (const __attribute__((address_space(1))) unsigned int*)(const void*)(g), \
        (__attribute__((address_space(3))) unsigned int*)(void*)(l), 16, 0, 0)

    for (int k0 = 0; k0 < K; k0 += 32) {
        __syncthreads();
        GLDS(a0 + k0, lA0);
        GLDS(a1 + k0, lA1);
        GLDS(b0 + k0, lB0);
        GLDS(b1 + k0, lB1);
        __syncthreads();

        bf16x8 af[4], bfr[4];
        #pragma unroll
        for (int i = 0; i < 4; ++i) {
            af[i]  = *(const bf16x8*)&As[(wrow + i * 16 + fr) * 32 + fq * 8];
            bfr[i] = *(const bf16x8*)&Bs[(wcol + i * 16 + fr) * 32 + fq * 8];
        }
        #pragma unroll
        for (int mi = 0; mi < 4; ++mi)
            #pragma unroll
            for (int ni = 0; ni < 4; ++ni)
                acc[mi][ni] = __builtin_amdgcn_mfma_f32_16x16x32_bf16(
                    af[mi], bfr[ni], acc[mi][ni], 0, 0, 0);
    }
#undef GLDS

    float bj[4] = {0.f, 0.f, 0.f, 0.f};
    if (flags & 1) {
        #pragma unroll
        for (int ni = 0; ni < 4; ++ni) bj[ni] = bias[bn0 + wcol + ni * 16 + fr];
    }
    bool relu = flags & 2;
    bool qkvm = flags & 4;
    #pragma unroll
    for (int mi = 0; mi < 4; ++mi) {
        int row0 = bm0 + wrow + mi * 16 + fq * 4;
        #pragma unroll
        for (int ni = 0; ni < 4; ++ni) {
            int col = bn0 + wcol + ni * 16 + fr;
            float v[4];
            #pragma unroll
            for (int r = 0; r < 4; ++r) {
                v[r] = acc[mi][ni][r] + bj[ni];
                if (relu) v[r] = fmaxf(v[r], 0.f);
            }
            if (qkvm) {
                if (col < 1024) {          // q|k row-major, stride cn=1024
                    #pragma unroll
                    for (int r = 0; r < 4; ++r)
                        Cb[(size_t)(row0 + r) * cn + col] = f2b(v[r]);
                } else {                   // v -> vT[(b*8+m)*64+d][l]
                    int mm = (col - 1024) >> 6, dd = (col - 1024) & 63;
                    int bb = row0 >> 10, l0 = row0 & 1023;
                    us4 p;
                    p.x = f2b(v[0]); p.y = f2b(v[1]); p.z = f2b(v[2]); p.w = f2b(v[3]);
                    *(us4*)&vT[((size_t)(bb * 8 + mm) * 64 + dd) * 1024 + l0] = p;
                }
            } else {
                #pragma unroll
                for (int r = 0; r < 4; ++r) {
                    if (Cf) Cf[(size_t)(row0 + r) * cn + col] = v[r];
                    if (Cb) Cb[(size_t)(row0 + r) * cn + col] = f2b(v[r]);
                }
            }
        }
    }
}

// ---------------------------------------------------------------------------
// MFMA flash attention. qk: [BL][1024] bf16 (q cols 0..511, k cols 512..1023,
// head m at m*64). vT: [(b*8+m)*64+d][1024 l] bf16. t out: [BL][512] bf16.
// 4 waves/WG, 16 q-rows per wave, KV tiles of 64, no-max softmax.
#define KST 72    // LDS row stride (elems): 144 B spreads b128 pattern over banks
__global__ __launch_bounds__(256) void attn_mfma_kernel(
    const unsigned short* __restrict__ qk, const unsigned short* __restrict__ vT,
    unsigned short* __restrict__ t)
{
    __shared__ unsigned short Ks[64 * KST];   // [key][d]
    __shared__ unsigned short Vs[64 * KST];   // [d][key]
    __shared__ unsigned short Pb[4][16 * KST];// per-wave [q][key]

    int tid = threadIdx.x;
    int lane = tid & 63, wid = tid >> 6;
    int fr = lane & 15, fq = lane >> 4;
    int b = blockIdx.z, m = blockIdx.y, q0 = blockIdx.x * 64;
    int bq = b * L_;

    // Q A-frags for this wave's 16 rows (row=fr, k=d=fq*8+reg, halves h*32)
    size_t qrow = (size_t)(bq + q0 + wid * 16 + fr) * 1024 + m * 64;
    bf16x8 qa[2];
    qa[0] = *(const bf16x8*)&qk[qrow + fq * 8];
    qa[1] = *(const bf16x8*)&qk[qrow + 32 + fq * 8];

    f32x4 oacc[4];
    #pragma unroll
    for (int i = 0; i < 4; ++i) oacc[i] = (f32x4){0.f, 0.f, 0.f, 0.f};
    float lsum[4] = {0.f, 0.f, 0.f, 0.f};

    int srow = tid >> 3;            // staging: row 0..31 (granule tid), +32 (tid+256)
    int scol = (tid & 7) * 8;       // 8 bf16 = 16B
    const unsigned short* kg = qk + (size_t)(bq) * 1024 + 512 + m * 64 + scol;
    const unsigned short* vg = vT + ((size_t)(b * 8 + m) * 64) * 1024 + scol;
    unsigned short* pw = Pb[wid];

    for (int kt = 0; kt < L_ / 64; ++kt) {
        int kb = kt * 64;
        uint4 k0 = *(const uint4*)&kg[(size_t)(kb + srow) * 1024];
        uint4 k1 = *(const uint4*)&kg[(size_t)(kb + srow + 32) * 1024];
        uint4 v0 = *(const uint4*)&vg[(size_t)(srow) * 1024 + kb];
        uint4 v1 = *(const uint4*)&vg[(size_t)(srow + 32) * 1024 + kb];
        __syncthreads();                       // prev tile's reads done
        *(uint4*)&Ks[(srow)      * KST + scol] = k0;
        *(uint4*)&Ks[(srow + 32) * KST + scol] = k1;
        *(uint4*)&Vs[(srow)      * KST + scol] = v0;
        *(uint4*)&Vs[(srow + 32) * KST + scol] = v1;
        __syncthreads();                       // tile staged

        // S = q k^T (scaled later), 4 key-16 blocks
        #pragma unroll
        for (int nk = 0; nk < 4; ++nk) {
            bf16x8 kf0 = *(const bf16x8*)&Ks[(nk * 16 + fr) * KST + fq * 8];
            bf16x8 kf1 = *(const bf16x8*)&Ks[(nk * 16 + fr) * KST + 32 + fq * 8];
            f32x4 s = __builtin_amdgcn_mfma_f32_16x16x32_bf16(
                qa[0], kf0, (f32x4){0.f, 0.f, 0.f, 0.f}, 0, 0, 0);
            s = __builtin_amdgcn_mfma_f32_16x16x32_bf16(qa[1], kf1, s, 0, 0, 0);
            #pragma unroll
            for (int r = 0; r < 4; ++r) {
                float p = __expf(s[r] * 0.125f);
                lsum[r] += p;
                pw[(fq * 4 + r) * KST + nk * 16 + fr] = f2b(p);
            }
        }
        // PV: A = P[16][64] (row=fr), B = V (col=d via Vs rows)
        bf16x8 pa0 = *(const bf16x8*)&pw[fr * KST + fq * 8];
        bf16x8 pa1 = *(const bf16x8*)&pw[fr * KST + 32 + fq * 8];
        #pragma unroll
        for (int nt = 0; nt < 4; ++nt) {
            bf16x8 vf0 = *(const bf16x8*)&Vs[(nt * 16 + fr) * KST + fq * 8];
            bf16x8 vf1 = *(const bf16x8*)&Vs[(nt * 16 + fr) * KST + 32 + fq * 8];
            oacc[nt] = __builtin_amdgcn_mfma_f32_16x16x32_bf16(pa0, vf0, oacc[nt], 0, 0, 0);
            oacc[nt] = __builtin_amdgcn_mfma_f32_16x16x32_bf16(pa1, vf1, oacc[nt], 0, 0, 0);
        }
    }

    // reduce denominators across the 16 fr-lanes of this fq-group
    #pragma unroll
    for (int r = 0; r < 4; ++r) {
        float s = lsum[r];
        s += __shfl_xor(s, 1); s += __shfl_xor(s, 2);
        s += __shfl_xor(s, 4); s += __shfl_xor(s, 8);
        lsum[r] = 1.f / s;
    }
    // write t rows q0+wid*16+fq*4+r, cols m*64 + nt*16 + fr
    #pragma unroll
    for (int r = 0; r < 4; ++r) {
        size_t orow = (size_t)(bq + q0 + wid * 16 + fq * 4 + r) * DH_ + m * 64;
        #pragma unroll
        for (int nt = 0; nt < 4; ++nt)
            t[orow + nt * 16 + fr] = f2b(oacc[nt][r] * lsum[r]);
    }
}

// ---------------------------------------------------------------------------
__global__ __launch_bounds__(256) void bn_stats_kernel(
    const float* __restrict__ a, const float* __restrict__ b,
    float* __restrict__ stats)
{
    int l = blockIdx.x, tid = threadIdx.x;
    float s = 0.f, s2 = 0.f;
    #pragma unroll
    for (int bb = 0; bb < B_; ++bb) {
        size_t off = ((size_t)bb * L_ + l) * DH_ + tid * 2;
        float2 va = *(const float2*)&a[off];
        float2 vb = *(const float2*)&b[off];
        float z0 = va.x + vb.x, z1 = va.y + vb.y;
        s += z0 + z1;
        s2 = fmaf(z0, z0, fmaf(z1, z1, s2));
    }
    #pragma unroll
    for (int off = 32; off > 0; off >>= 1) {
        s  += __shfl_down(s, off);
        s2 += __shfl_down(s2, off);
    }
    __shared__ float red[8];
    int w = tid >> 6;
    if ((tid & 63) == 0) { red[w] = s; red[4 + w] = s2; }
    __syncthreads();
    if (tid == 0) {
        float S  = red[0] + red[1] + red[2] + red[3];
        float S2 = red[4] + red[5] + red[6] + red[7];
        float mu  = S * (1.f / 8192.f);
        float var = S2 * (1.f / 8192.f) - mu * mu;
        stats[l]      = mu;
        stats[L_ + l] = rsqrtf(var + 1e-5f);
    }
}

__global__ __launch_bounds__(256) void bn_apply_kernel(
    const float* __restrict__ a, const float* __restrict__ b,
    const float* __restrict__ stats, const float* __restrict__ w,
    const float* __restrict__ bias, float* __restrict__ out,
    unsigned short* __restrict__ outb)
{
    int idx = blockIdx.x * 256 + threadIdx.x;
    int bl = idx >> 7;
    int d4 = (idx & 127) << 2;
    int l  = bl & (L_ - 1);
    float mu = stats[l], rs = stats[L_ + l];
    size_t off = (size_t)bl * DH_ + d4;
    float4 va = *(const float4*)&a[off];
    float4 vb = *(const float4*)&b[off];
    float4 vw = *(const float4*)&w[d4];
    float4 vc = *(const float4*)&bias[d4];
    float4 o;
    o.x = fmaf(vw.x, ((va.x + vb.x) - mu) * rs, vc.x);
    o.y = fmaf(vw.y, ((va.y + vb.y) - mu) * rs, vc.y);
    o.z = fmaf(vw.z, ((va.z + vb.z) - mu) * rs, vc.z);
    o.w = fmaf(vw.w, ((va.w + vb.w) - mu) * rs, vc.w);
    *(float4*)&out[off] = o;
    if (outb) {
        us4 ub;
        ub.x = f2b(o.x); ub.y = f2b(o.y); ub.z = f2b(o.z); ub.w = f2b(o.w);
        *(us4*)&outb[off] = ub;
    }
}

// ---------------------------------------------------------------------------
extern "C" void kernel_launch(void* const* d_in, const int* in_sizes, int n_in,
                              void* d_out, int out_size, void* d_ws, size_t ws_size,
                              hipStream_t stream)
{
    const float* x    = (const float*)d_in[0];
    const float* Wh   = (const float*)d_in[1];
    const float* bh   = (const float*)d_in[2];
    const float* Wq   = (const float*)d_in[3];
    const float* Wk   = (const float*)d_in[4];
    const float* Wv   = (const float*)d_in[5];
    const float* Wo   = (const float*)d_in[6];
    const float* wbn  = (const float*)d_in[7];
    const float* bbn  = (const float*)d_in[8];
    const float* Wff0 = (const float*)d_in[9];
    const float* bff0 = (const float*)d_in[10];
    const float* Wff1 = (const float*)d_in[11];
    const float* bff1 = (const float*)d_in[12];
    float* out = (float*)d_out;

    // Workspace (~181 MB):
    //  fp32: h 32MB | b0 32MB (h_mha, later ff-out) | st 8KB.  b1 := d_out (32MB).
    //  bf16: hb 16 | qkkb[BL][1024] 32 | vT 16 | tbb 16 | ffmb[8192][2048] 32
    //        wqkvb 1.5 | wob 0.5 | wff0b 2 | wff1b 2
    float* ws = (float*)d_ws;
    const size_t SZ = (size_t)BL_ * DH_;
    float* h  = ws;
    float* b0 = h + SZ;
    float* st = b0 + SZ;
    unsigned short* hb    = (unsigned short*)(st + 2048);
    unsigned short* qkkb  = hb + SZ;
    unsigned short* vTb   = qkkb + (size_t)BL_ * 1024;
    unsigned short* tbb   = vTb + SZ;
    unsigned short* ffmb  = tbb + SZ;
    unsigned short* wqkvb = ffmb + (size_t)FFCH_ * DFF_;
    unsigned short* wob   = wqkvb + 1536 * 512;
    unsigned short* wff0b = wob + 512 * 512;
    unsigned short* wff1b = wff0b + (size_t)DFF_ * DH_;
    float* b1 = out;            // h_bn fp32 (in-place-safe for final bn_apply)
    float* b2 = b0;             // ff out reuses h_mha space

    embed_kernel<<<BL_ * DH_ / 256, 256, 0, stream>>>(x, Wh, bh, h, hb);

    dim3 gqkv(1536 / 128, BL_ / 128);
    dim3 gwo(DH_ / 128, BL_ / 128);
    dim3 gff0(DFF_ / 128, FFCH_ / 128);
    dim3 gff1(DH_ / 128, FFCH_ / 128);
    dim3 gattn(L_ / 64, M_, B_);
    int gbn = BL_ * DH_ / 4 / 256;
    const int WSZ = DK_ * DH_ * M_;

    for (int n = 0; n < NL_; ++n) {
        const float* Wo_n   = Wo   + (size_t)n * M_ * DH_ * DK_;
        const float* wbn_n  = wbn  + (size_t)n * DH_;
        const float* bbn_n  = bbn  + (size_t)n * DH_;
        const float* bff0_n = bff0 + (size_t)n * DFF_;
        const float* bff1_n = bff1 + (size_t)n * DH_;

        cvt_f2b_kernel<<<WSZ / 1024, 256, 0, stream>>>(Wq + (size_t)n * WSZ, wqkvb);
        cvt_f2b_kernel<<<WSZ / 1024, 256, 0, stream>>>(Wk + (size_t)n * WSZ, wqkvb + WSZ);
        cvt_f2b_kernel<<<WSZ / 1024, 256, 0, stream>>>(Wv + (size_t)n * WSZ, wqkvb + 2 * WSZ);
        repack_wo_kernel<<<DH_ * DH_ / 256, 256, 0, stream>>>(Wo_n, wob);
        cvt_f2b_kernel<<<DFF_ * DH_ / 1024, 256, 0, stream>>>(Wff0 + (size_t)n * DFF_ * DH_, wff0b);
        cvt_f2b_kernel<<<DFF_ * DH_ / 1024, 256, 0, stream>>>(Wff1 + (size_t)n * DH_ * DFF_, wff1b);

        // qkv: q|k -> qkkb [BL][1024], v -> vTb transposed
        gemm_bf16_kernel<<<gqkv, 256, 0, stream>>>(hb, wqkvb, nullptr, nullptr,
            qkkb, vTb, 1536, DH_, 1024, 4);
        // t = softmax(q k^T / 8) v -> tbb bf16
        attn_mfma_kernel<<<gattn, 256, 0, stream>>>(qkkb, vTb, tbb);
        // h_mha = t @ wob^T -> b0 fp32
        gemm_bf16_kernel<<<gwo, 256, 0, stream>>>(tbb, wob, nullptr, b0,
            nullptr, nullptr, DH_, DH_, DH_, 0);
        // h_bn = w*BN(h + h_mha) + b -> b1 fp32 + tbb bf16
        bn_stats_kernel<<<L_, 256, 0, stream>>>(h, b0, st);
        bn_apply_kernel<<<gbn, 256, 0, stream>>>(h, b0, st, wbn_n, bbn_n, b1, tbb);
        // ff = relu(h_bn @ Wff0^T + bff0) @ Wff1^T + bff1 -> b2
        for (int r0 = 0; r0 < BL_; r0 += FFCH_) {
            gemm_bf16_kernel<<<gff0, 256, 0, stream>>>(tbb + (size_t)r0 * DH_, wff0b,
                bff0_n, nullptr, ffmb, nullptr, DFF_, DH_, DFF_, 1 | 2);
            gemm_bf16_kernel<<<gff1, 256, 0, stream>>>(ffmb, wff1b,
                bff1_n, b2 + (size_t)r0 * DH_, nullptr, nullptr, DH_, DFF_, DH_, 1);
        }
        // h = w*BN(h_bn + ff) + b
        bn_stats_kernel<<<L_, 256, 0, stream>>>(b1, b2, st);
        bn_apply_kernel<<<gbn, 256, 0, stream>>>(b1, b2, st, wbn_n, bbn_n,
            (n == NL_ - 1) ? out : h, (n == NL_ - 1) ? nullptr : hb);
    }
}

// Round 5
// 854.312 us; speedup vs baseline: 9.8603x; 1.3571x over previous
//
#include <hip/hip_runtime.h>
#include <hip/hip_bf16.h>
#include <math.h>

// Problem constants (Encoder_24816321036413)
#define B_   16
#define L_   1024
#define BL_  16384      // B_*L_
#define DH_  512
#define DFF_ 2048
#define NL_  3
#define M_   8
#define DK_  64

typedef __attribute__((ext_vector_type(8))) short bf16x8;
typedef __attribute__((ext_vector_type(4))) float f32x4;
typedef __attribute__((ext_vector_type(4))) unsigned short us4;
typedef __attribute__((ext_vector_type(8))) unsigned short us8;

__device__ __forceinline__ unsigned short f2b(float x) {
    __hip_bfloat16 h = __float2bfloat16(x);   // RNE
    return *(unsigned short*)&h;
}
__device__ __forceinline__ float b2f(unsigned short u) {
    unsigned int v = ((unsigned int)u) << 16;
    return __builtin_bit_cast(float, v);
}

// ---------------------------------------------------------------------------
// One-shot weight prep for ALL layers: Wq|Wk|Wv -> wqkvb3 [n][1536][512],
// Wo repack -> wob3 [n][512 d][512 mv], Wff0 -> wff0b3, Wff1 -> wff1b3 (bf16).
#define QKV_T 2359296   // 3 layers * 3 mats * 262144
#define WO_T  786432
#define FF_T  3145728   // 3 * 2048*512
__global__ __launch_bounds__(256) void wprep_kernel(
    const float* __restrict__ Wq, const float* __restrict__ Wk,
    const float* __restrict__ Wv, const float* __restrict__ Wo,
    const float* __restrict__ Wff0, const float* __restrict__ Wff1,
    unsigned short* __restrict__ wqkvb3, unsigned short* __restrict__ wob3,
    unsigned short* __restrict__ wff0b3, unsigned short* __restrict__ wff1b3)
{
    int i4 = (blockIdx.x * 256 + threadIdx.x) * 4;
    const float* src;
    unsigned short* dst;
    if (i4 < QKV_T) {
        int n = i4 / 786432, r = i4 % 786432;
        if (r < 262144)      src = Wq + (size_t)n * 262144 + r;
        else if (r < 524288) src = Wk + (size_t)n * 262144 + r - 262144;
        else                 src = Wv + (size_t)n * 262144 + r - 524288;
        dst = wqkvb3 + i4;
    } else if (i4 < QKV_T + WO_T) {
        int i = i4 - QKV_T;
        int n = i / 262144, r = i % 262144;
        int d = r >> 9, mv = r & 511, mm = mv >> 6, vv = mv & 63;
        src = Wo + (size_t)n * 262144 + ((size_t)mm * 512 + d) * 64 + vv;
        dst = wob3 + i;
    } else if (i4 < QKV_T + WO_T + FF_T) {
        int i = i4 - QKV_T - WO_T;
        src = Wff0 + i;
        dst = wff0b3 + i;
    } else {
        int i = i4 - QKV_T - WO_T - FF_T;
        src = Wff1 + i;
        dst = wff1b3 + i;
    }
    float4 v = *(const float4*)src;
    us4 o;
    o.x = f2b(v.x); o.y = f2b(v.y); o.z = f2b(v.z); o.w = f2b(v.w);
    *(us4*)dst = o;
}

// ---------------------------------------------------------------------------
// h[bl][e] bf16 only (fp32 copy never needed: all consumers are bf16)
__global__ __launch_bounds__(256) void embed_kernel(
    const float* __restrict__ x, const float* __restrict__ Wh,
    const float* __restrict__ bh, unsigned short* __restrict__ hb)
{
    int idx = blockIdx.x * 256 + threadIdx.x;   // BL_*DH_/4
    int bl = idx >> 7;
    int e0 = (idx & 127) * 4;
    float x0 = x[bl * 2], x1 = x[bl * 2 + 1];
    us4 o;
    #pragma unroll
    for (int r = 0; r < 4; ++r) {
        int e = e0 + r;
        float v = fmaf(x0, Wh[e * 2], fmaf(x1, Wh[e * 2 + 1], bh[e]));
        ((unsigned short*)&o)[r] = f2b(v);
    }
    *(us4*)&hb[(size_t)bl * DH_ + e0] = o;
}

// ---------------------------------------------------------------------------
// MFMA bf16 GEMM-NT: C[M x N] = A[M x K] * B[N x K]^T  (m97 structure).
// flags: bit0 bias, bit1 relu, bit2 qkv-mode (cols<1024 -> Cb stride cn,
//        cols>=1024 -> vT[(b*8+m)*64+d][l] transposed scatter).
__global__ __launch_bounds__(256) void gemm_bf16_kernel(
    const unsigned short* __restrict__ A, const unsigned short* __restrict__ Bm,
    const float* __restrict__ bias, unsigned short* __restrict__ Cb,
    unsigned short* __restrict__ vT, int N, int K, int cn, int flags)
{
    __shared__ unsigned short As[128 * 32];
    __shared__ unsigned short Bs[128 * 32];

    int tid  = threadIdx.x;
    int lane = tid & 63, wid = tid >> 6;
    int bm0 = blockIdx.y * 128, bn0 = blockIdx.x * 128;
    int wrow = (wid >> 1) * 64, wcol = (wid & 1) * 64;
    int fr = lane & 15, fq = lane >> 4;

    f32x4 acc[4][4];
    #pragma unroll
    for (int i = 0; i < 4; ++i)
        #pragma unroll
        for (int j = 0; j < 4; ++j)
            acc[i][j] = (f32x4){0.f, 0.f, 0.f, 0.f};

    const unsigned short* a0 = A + (size_t)(bm0 +      (tid >> 2)) * K + (tid & 3) * 8;
    const unsigned short* a1 = A + (size_t)(bm0 + 64 + (tid >> 2)) * K + (tid & 3) * 8;
    const unsigned short* b0 = Bm + (size_t)(bn0 +      (tid >> 2)) * K + (tid & 3) * 8;
    const unsigned short* b1 = Bm + (size_t)(bn0 + 64 + (tid >> 2)) * K + (tid & 3) * 8;
    unsigned short* lA0 = As + wid * 512;
    unsigned short* lA1 = As + 2048 + wid * 512;
    unsigned short* lB0 = Bs + wid * 512;
    unsigned short* lB1 = Bs + 2048 + wid * 512;

#define GLDS(g, l) __builtin_amdgcn_global_load_lds( \
        (const __attribute__((address_space(1))) unsigned int*)(const void*)(g), \
        (__attribute__((address_space(3))) unsigned int*)(void*)(l), 16, 0, 0)

    for (int k0 = 0; k0 < K; k0 += 32) {
        __syncthreads();
        GLDS(a0 + k0, lA0);
        GLDS(a1 + k0, lA1);
        GLDS(b0 + k0, lB0);
        GLDS(b1 + k0, lB1);
        __syncthreads();

        bf16x8 af[4], bfr[4];
        #pragma unroll
        for (int i = 0; i < 4; ++i) {
            af[i]  = *(const bf16x8*)&As[(wrow + i * 16 + fr) * 32 + fq * 8];
            bfr[i] = *(const bf16x8*)&Bs[(wcol + i * 16 + fr) * 32 + fq * 8];
        }
        #pragma unroll
        for (int mi = 0; mi < 4; ++mi)
            #pragma unroll
            for (int ni = 0; ni < 4; ++ni)
                acc[mi][ni] = __builtin_amdgcn_mfma_f32_16x16x32_bf16(
                    af[mi], bfr[ni], acc[mi][ni], 0, 0, 0);
    }
#undef GLDS

    float bj[4] = {0.f, 0.f, 0.f, 0.f};
    if (flags & 1) {
        #pragma unroll
        for (int ni = 0; ni < 4; ++ni) bj[ni] = bias[bn0 + wcol + ni * 16 + fr];
    }
    bool relu = flags & 2;
    bool qkvm = flags & 4;
    #pragma unroll
    for (int mi = 0; mi < 4; ++mi) {
        int row0 = bm0 + wrow + mi * 16 + fq * 4;
        #pragma unroll
        for (int ni = 0; ni < 4; ++ni) {
            int col = bn0 + wcol + ni * 16 + fr;
            float v[4];
            #pragma unroll
            for (int r = 0; r < 4; ++r) {
                v[r] = acc[mi][ni][r] + bj[ni];
                if (relu) v[r] = fmaxf(v[r], 0.f);
            }
            if (qkvm) {
                if (col < 1024) {          // q|k row-major, stride cn
                    #pragma unroll
                    for (int r = 0; r < 4; ++r)
                        Cb[(size_t)(row0 + r) * cn + col] = f2b(v[r]);
                } else {                   // v -> vT[(b*8+m)*64+d][l]
                    int mm = (col - 1024) >> 6, dd = (col - 1024) & 63;
                    int bb = row0 >> 10, l0 = row0 & 1023;
                    us4 p;
                    p.x = f2b(v[0]); p.y = f2b(v[1]); p.z = f2b(v[2]); p.w = f2b(v[3]);
                    *(us4*)&vT[((size_t)(bb * 8 + mm) * 64 + dd) * 1024 + l0] = p;
                }
            } else {
                #pragma unroll
                for (int r = 0; r < 4; ++r)
                    Cb[(size_t)(row0 + r) * cn + col] = f2b(v[r]);
            }
        }
    }
}

// ---------------------------------------------------------------------------
// MFMA flash attention, prefetched staging. qk: [BL][1024] bf16, vT transposed.
#define KST 72
__global__ __launch_bounds__(256) void attn_mfma_kernel(
    const unsigned short* __restrict__ qk, const unsigned short* __restrict__ vT,
    unsigned short* __restrict__ t)
{
    __shared__ unsigned short Ks[64 * KST];   // [key][d]
    __shared__ unsigned short Vs[64 * KST];   // [d][key]
    __shared__ unsigned short Pb[4][16 * KST];// per-wave [q][key]

    int tid = threadIdx.x;
    int lane = tid & 63, wid = tid >> 6;
    int fr = lane & 15, fq = lane >> 4;
    int b = blockIdx.z, m = blockIdx.y, q0 = blockIdx.x * 64;
    int bq = b * L_;

    size_t qrow = (size_t)(bq + q0 + wid * 16 + fr) * 1024 + m * 64;
    bf16x8 qa[2];
    qa[0] = *(const bf16x8*)&qk[qrow + fq * 8];
    qa[1] = *(const bf16x8*)&qk[qrow + 32 + fq * 8];

    f32x4 oacc[4];
    #pragma unroll
    for (int i = 0; i < 4; ++i) oacc[i] = (f32x4){0.f, 0.f, 0.f, 0.f};
    float lsum[4] = {0.f, 0.f, 0.f, 0.f};

    int srow = tid >> 3;
    int scol = (tid & 7) * 8;
    const unsigned short* kg = qk + (size_t)bq * 1024 + 512 + m * 64 + scol;
    const unsigned short* vg = vT + ((size_t)(b * 8 + m) * 64) * 1024 + scol;
    unsigned short* pw = Pb[wid];

    // prefetch tile 0
    uint4 k0 = *(const uint4*)&kg[(size_t)(srow) * 1024];
    uint4 k1 = *(const uint4*)&kg[(size_t)(srow + 32) * 1024];
    uint4 v0 = *(const uint4*)&vg[(size_t)(srow) * 1024];
    uint4 v1 = *(const uint4*)&vg[(size_t)(srow + 32) * 1024];

    for (int kt = 0; kt < L_ / 64; ++kt) {
        __syncthreads();                       // prev tile's reads done
        *(uint4*)&Ks[(srow)      * KST + scol] = k0;
        *(uint4*)&Ks[(srow + 32) * KST + scol] = k1;
        *(uint4*)&Vs[(srow)      * KST + scol] = v0;
        *(uint4*)&Vs[(srow + 32) * KST + scol] = v1;
        __syncthreads();                       // tile staged
        if (kt + 1 < L_ / 64) {                // prefetch next tile under compute
            int kb = (kt + 1) * 64;
            k0 = *(const uint4*)&kg[(size_t)(kb + srow) * 1024];
            k1 = *(const uint4*)&kg[(size_t)(kb + srow + 32) * 1024];
            v0 = *(const uint4*)&vg[(size_t)(srow) * 1024 + kb];
            v1 = *(const uint4*)&vg[(size_t)(srow + 32) * 1024 + kb];
        }

        __builtin_amdgcn_s_setprio(1);
        #pragma unroll
        for (int nk = 0; nk < 4; ++nk) {
            bf16x8 kf0 = *(const bf16x8*)&Ks[(nk * 16 + fr) * KST + fq * 8];
            bf16x8 kf1 = *(const bf16x8*)&Ks[(nk * 16 + fr) * KST + 32 + fq * 8];
            f32x4 s = __builtin_amdgcn_mfma_f32_16x16x32_bf16(
                qa[0], kf0, (f32x4){0.f, 0.f, 0.f, 0.f}, 0, 0, 0);
            s = __builtin_amdgcn_mfma_f32_16x16x32_bf16(qa[1], kf1, s, 0, 0, 0);
            #pragma unroll
            for (int r = 0; r < 4; ++r) {
                float p = __expf(s[r] * 0.125f);
                lsum[r] += p;
                pw[(fq * 4 + r) * KST + nk * 16 + fr] = f2b(p);
            }
        }
        bf16x8 pa0 = *(const bf16x8*)&pw[fr * KST + fq * 8];
        bf16x8 pa1 = *(const bf16x8*)&pw[fr * KST + 32 + fq * 8];
        #pragma unroll
        for (int nt = 0; nt < 4; ++nt) {
            bf16x8 vf0 = *(const bf16x8*)&Vs[(nt * 16 + fr) * KST + fq * 8];
            bf16x8 vf1 = *(const bf16x8*)&Vs[(nt * 16 + fr) * KST + 32 + fq * 8];
            oacc[nt] = __builtin_amdgcn_mfma_f32_16x16x32_bf16(pa0, vf0, oacc[nt], 0, 0, 0);
            oacc[nt] = __builtin_amdgcn_mfma_f32_16x16x32_bf16(pa1, vf1, oacc[nt], 0, 0, 0);
        }
        __builtin_amdgcn_s_setprio(0);
    }

    #pragma unroll
    for (int r = 0; r < 4; ++r) {
        float s = lsum[r];
        s += __shfl_xor(s, 1); s += __shfl_xor(s, 2);
        s += __shfl_xor(s, 4); s += __shfl_xor(s, 8);
        lsum[r] = 1.f / s;
    }
    #pragma unroll
    for (int r = 0; r < 4; ++r) {
        size_t orow = (size_t)(bq + q0 + wid * 16 + fq * 4 + r) * DH_ + m * 64;
        #pragma unroll
        for (int nt = 0; nt < 4; ++nt)
            t[orow + nt * 16 + fr] = f2b(oacc[nt][r] * lsum[r]);
    }
}

// ---------------------------------------------------------------------------
// BatchNorm per position l over (batch, feature); z = a + b, a/b bf16.
__global__ __launch_bounds__(256) void bn_stats_kernel(
    const unsigned short* __restrict__ a, const unsigned short* __restrict__ b,
    float* __restrict__ stats)
{
    int l = blockIdx.x, tid = threadIdx.x;
    float s = 0.f, s2 = 0.f;
    #pragma unroll
    for (int u = tid; u < 1024; u += 256) {
        int bb = u >> 6, dg = (u & 63) * 8;
        size_t off = ((size_t)bb * L_ + l) * DH_ + dg;
        us8 va = *(const us8*)&a[off];
        us8 vb = *(const us8*)&b[off];
        #pragma unroll
        for (int j = 0; j < 8; ++j) {
            float z = b2f(va[j]) + b2f(vb[j]);
            s += z;
            s2 = fmaf(z, z, s2);
        }
    }
    #pragma unroll
    for (int off = 32; off > 0; off >>= 1) {
        s  += __shfl_down(s, off);
        s2 += __shfl_down(s2, off);
    }
    __shared__ float red[8];
    int w = tid >> 6;
    if ((tid & 63) == 0) { red[w] = s; red[4 + w] = s2; }
    __syncthreads();
    if (tid == 0) {
        float S  = red[0] + red[1] + red[2] + red[3];
        float S2 = red[4] + red[5] + red[6] + red[7];
        float mu  = S * (1.f / 8192.f);
        float var = S2 * (1.f / 8192.f) - mu * mu;
        stats[l]      = mu;
        stats[L_ + l] = rsqrtf(var + 1e-5f);
    }
}

// out = w*((a+b)-mu)*rstd + bias; bf16 out (outb) or fp32 out (outf), null-skip.
__global__ __launch_bounds__(256) void bn_apply_kernel(
    const unsigned short* __restrict__ a, const unsigned short* __restrict__ b,
    const float* __restrict__ stats, const float* __restrict__ w,
    const float* __restrict__ bias, unsigned short* __restrict__ outb,
    float* __restrict__ outf)
{
    int idx = blockIdx.x * 256 + threadIdx.x;   // BL_*DH_/8
    int bl = idx >> 6;
    int d0 = (idx & 63) * 8;
    int l  = bl & (L_ - 1);
    float mu = stats[l], rs = stats[L_ + l];
    size_t off = (size_t)bl * DH_ + d0;
    us8 va = *(const us8*)&a[off];
    us8 vb = *(const us8*)&b[off];
    float o[8];
    #pragma unroll
    for (int j = 0; j < 8; ++j) {
        float z = b2f(va[j]) + b2f(vb[j]);
        o[j] = fmaf(w[d0 + j], (z - mu) * rs, bias[d0 + j]);
    }
    if (outb) {
        us8 ob;
        #pragma unroll
        for (int j = 0; j < 8; ++j) ob[j] = f2b(o[j]);
        *(us8*)&outb[off] = ob;
    }
    if (outf) {
        float4 o0 = {o[0], o[1], o[2], o[3]};
        float4 o1 = {o[4], o[5], o[6], o[7]};
        *(float4*)&outf[off]     = o0;
        *(float4*)&outf[off + 4] = o1;
    }
}

// ---------------------------------------------------------------------------
extern "C" void kernel_launch(void* const* d_in, const int* in_sizes, int n_in,
                              void* d_out, int out_size, void* d_ws, size_t ws_size,
                              hipStream_t stream)
{
    const float* x    = (const float*)d_in[0];
    const float* Wh   = (const float*)d_in[1];
    const float* bh   = (const float*)d_in[2];
    const float* Wq   = (const float*)d_in[3];
    const float* Wk   = (const float*)d_in[4];
    const float* Wv   = (const float*)d_in[5];
    const float* Wo   = (const float*)d_in[6];
    const float* wbn  = (const float*)d_in[7];
    const float* bbn  = (const float*)d_in[8];
    const float* Wff0 = (const float*)d_in[9];
    const float* bff0 = (const float*)d_in[10];
    const float* Wff1 = (const float*)d_in[11];
    const float* bff1 = (const float*)d_in[12];
    float* out = (float*)d_out;

    // Workspace (~146 MB), all activations bf16:
    //   st 8KB | hb 16MB | qkkb 32MB | vTb 16MB | tb 16MB | mhab 16MB
    //   hbnb 16MB | ffob 16MB | weights 18MB
    //   ffmb [BL][DFF] 64MB ALIASES qkkb+vTb+tb (dead when FF0 runs)
    float* st = (float*)d_ws;
    unsigned short* hb    = (unsigned short*)(st + 2048);
    unsigned short* qkkb  = hb + (size_t)BL_ * DH_;
    unsigned short* vTb   = qkkb + (size_t)BL_ * 1024;
    unsigned short* tb    = vTb + (size_t)BL_ * DH_;
    unsigned short* mhab  = tb + (size_t)BL_ * DH_;
    unsigned short* hbnb  = mhab + (size_t)BL_ * DH_;
    unsigned short* ffob  = hbnb + (size_t)BL_ * DH_;
    unsigned short* wqkvb3 = ffob + (size_t)BL_ * DH_;
    unsigned short* wob3   = wqkvb3 + QKV_T;
    unsigned short* wff0b3 = wob3 + WO_T;
    unsigned short* wff1b3 = wff0b3 + FF_T;
    unsigned short* ffmb  = qkkb;    // alias: exactly 32M elems = qkkb+vTb+tb

    wprep_kernel<<<(QKV_T + WO_T + 2 * FF_T) / 1024, 256, 0, stream>>>(
        Wq, Wk, Wv, Wo, Wff0, Wff1, wqkvb3, wob3, wff0b3, wff1b3);
    embed_kernel<<<BL_ * DH_ / 4 / 256, 256, 0, stream>>>(x, Wh, bh, hb);

    dim3 gqkv(1536 / 128, BL_ / 128);
    dim3 gwo(DH_ / 128, BL_ / 128);
    dim3 gff0(DFF_ / 128, BL_ / 128);
    dim3 gff1(DH_ / 128, BL_ / 128);
    dim3 gattn(L_ / 64, M_, B_);
    int gbn = BL_ * DH_ / 8 / 256;

    for (int n = 0; n < NL_; ++n) {
        const unsigned short* wqkvb = wqkvb3 + (size_t)n * 786432;
        const unsigned short* wob   = wob3   + (size_t)n * 262144;
        const unsigned short* wff0b = wff0b3 + (size_t)n * 1048576;
        const unsigned short* wff1b = wff1b3 + (size_t)n * 1048576;
        const float* wbn_n  = wbn  + (size_t)n * DH_;
        const float* bbn_n  = bbn  + (size_t)n * DH_;
        const float* bff0_n = bff0 + (size_t)n * DFF_;
        const float* bff1_n = bff1 + (size_t)n * DH_;
        bool last = (n == NL_ - 1);

        // qkv: q|k -> qkkb [BL][1024], v -> vTb transposed
        gemm_bf16_kernel<<<gqkv, 256, 0, stream>>>(hb, wqkvb, nullptr,
            qkkb, vTb, 1536, DH_, 1024, 4);
        // t = softmax(q k^T / 8) v -> tb
        attn_mfma_kernel<<<gattn, 256, 0, stream>>>(qkkb, vTb, tb);
        // h_mha = t @ wob^T -> mhab
        gemm_bf16_kernel<<<gwo, 256, 0, stream>>>(tb, wob, nullptr,
            mhab, nullptr, DH_, DH_, DH_, 0);
        // h_bn = w*BN(h + h_mha) + b -> hbnb
        bn_stats_kernel<<<L_, 256, 0, stream>>>(hb, mhab, st);
        bn_apply_kernel<<<gbn, 256, 0, stream>>>(hb, mhab, st, wbn_n, bbn_n,
            hbnb, nullptr);
        // ff = relu(h_bn @ Wff0^T + bff0) @ Wff1^T + bff1 -> ffob
        gemm_bf16_kernel<<<gff0, 256, 0, stream>>>(hbnb, wff0b, bff0_n,
            ffmb, nullptr, DFF_, DH_, DFF_, 1 | 2);
        gemm_bf16_kernel<<<gff1, 256, 0, stream>>>(ffmb, wff1b, bff1_n,
            ffob, nullptr, DH_, DFF_, DH_, 1);
        // h = w*BN(h_bn + ff) + b  (final layer -> fp32 d_out)
        bn_stats_kernel<<<L_, 256, 0, stream>>>(hbnb, ffob, st);
        bn_apply_kernel<<<gbn, 256, 0, stream>>>(hbnb, ffob, st, wbn_n, bbn_n,
            last ? nullptr : hb, last ? out : nullptr);
    }
}

// Round 6
// 805.984 us; speedup vs baseline: 10.4516x; 1.0600x over previous
//
#include <hip/hip_runtime.h>
#include <hip/hip_bf16.h>
#include <math.h>

// Problem constants (Encoder_24816321036413)
#define B_   16
#define L_   1024
#define BL_  16384      // B_*L_
#define DH_  512
#define DFF_ 2048
#define NL_  3
#define M_   8
#define DK_  64

typedef __attribute__((ext_vector_type(8))) short bf16x8;
typedef __attribute__((ext_vector_type(4))) float f32x4;
typedef __attribute__((ext_vector_type(4))) unsigned short us4;
typedef __attribute__((ext_vector_type(8))) unsigned short us8;

__device__ __forceinline__ unsigned short f2b(float x) {
    __hip_bfloat16 h = __float2bfloat16(x);   // RNE
    return *(unsigned short*)&h;
}
__device__ __forceinline__ float b2f(unsigned short u) {
    unsigned int v = ((unsigned int)u) << 16;
    return __builtin_bit_cast(float, v);
}

#define GLDS(g, l) __builtin_amdgcn_global_load_lds( \
        (const __attribute__((address_space(1))) unsigned int*)(const void*)(g), \
        (__attribute__((address_space(3))) unsigned int*)(void*)(l), 16, 0, 0)

// ---------------------------------------------------------------------------
// One-shot weight prep (all layers): QKV fuse, Wo repack, FF0/FF1 cvt -> bf16
#define QKV_T 2359296   // 3 layers * 3 mats * 262144
#define WO_T  786432
#define FF_T  3145728   // 3 * 2048*512
__global__ __launch_bounds__(256) void wprep_kernel(
    const float* __restrict__ Wq, const float* __restrict__ Wk,
    const float* __restrict__ Wv, const float* __restrict__ Wo,
    const float* __restrict__ Wff0, const float* __restrict__ Wff1,
    unsigned short* __restrict__ wqkvb3, unsigned short* __restrict__ wob3,
    unsigned short* __restrict__ wff0b3, unsigned short* __restrict__ wff1b3)
{
    int i4 = (blockIdx.x * 256 + threadIdx.x) * 4;
    const float* src;
    unsigned short* dst;
    if (i4 < QKV_T) {
        int n = i4 / 786432, r = i4 % 786432;
        if (r < 262144)      src = Wq + (size_t)n * 262144 + r;
        else if (r < 524288) src = Wk + (size_t)n * 262144 + r - 262144;
        else                 src = Wv + (size_t)n * 262144 + r - 524288;
        dst = wqkvb3 + i4;
    } else if (i4 < QKV_T + WO_T) {
        int i = i4 - QKV_T;
        int n = i / 262144, r = i % 262144;
        int d = r >> 9, mv = r & 511, mm = mv >> 6, vv = mv & 63;
        src = Wo + (size_t)n * 262144 + ((size_t)mm * 512 + d) * 64 + vv;
        dst = wob3 + i;
    } else if (i4 < QKV_T + WO_T + FF_T) {
        int i = i4 - QKV_T - WO_T;
        src = Wff0 + i;
        dst = wff0b3 + i;
    } else {
        int i = i4 - QKV_T - WO_T - FF_T;
        src = Wff1 + i;
        dst = wff1b3 + i;
    }
    float4 v = *(const float4*)src;
    us4 o;
    o.x = f2b(v.x); o.y = f2b(v.y); o.z = f2b(v.z); o.w = f2b(v.w);
    *(us4*)dst = o;
}

// ---------------------------------------------------------------------------
__global__ __launch_bounds__(256) void embed_kernel(
    const float* __restrict__ x, const float* __restrict__ Wh,
    const float* __restrict__ bh, unsigned short* __restrict__ hb)
{
    int idx = blockIdx.x * 256 + threadIdx.x;   // BL_*DH_/4
    int bl = idx >> 7;
    int e0 = (idx & 127) * 4;
    float x0 = x[bl * 2], x1 = x[bl * 2 + 1];
    us4 o;
    #pragma unroll
    for (int r = 0; r < 4; ++r) {
        int e = e0 + r;
        float v = fmaf(x0, Wh[e * 2], fmaf(x1, Wh[e * 2 + 1], bh[e]));
        ((unsigned short*)&o)[r] = f2b(v);
    }
    *(us4*)&hb[(size_t)bl * DH_ + e0] = o;
}

// ---------------------------------------------------------------------------
// 8-phase 256xBN bf16 GEMM-NT (HK schedule port, provable wait ledger).
// C[M x N] = A[M x K] * B[N x K]^T.  NF = n-frags/wave: 4 -> BN=256, 2 -> BN=128.
// 512 thr = 8 waves (2M x 4N); per-wave out 128 x NF*16.  BK=64, dbuf 2 slots.
// LDS swizzle (T2): linear gload_lds dest + pre-swz source col ((t&7)^((t>>3)&7))
// + read-side XOR ((fr&7)<<4) -- same 16B involution both sides.
// Wait ledger (per-wave FIFO, order [B sweeps | A s0 sweeps | A s1 sweeps]):
//   group start: vmcnt(2) before barrier -> B + A-s0 landed (A-s1 in flight)
//   end ph1:     vmcnt(4) (last tile: 0)  -> A-s1 landed before ph2 reads
//   end ph3:     vmcnt(2)                 -> next tile's B + A-s0 landed
// Every wait precedes an s_barrier => cross-wave chunk visibility guaranteed.
// flags: bit0 bias, bit1 relu, bit2 qkv-mode (col<1024 -> Cb stride cn,
//        col>=1024 -> vT[(b*8+m)*64+d][l] transposed scatter).
template<int NF>
__global__ __launch_bounds__(512, 2) void gemm8p_kernel(
    const unsigned short* __restrict__ A, const unsigned short* __restrict__ Bm,
    const float* __restrict__ bias, unsigned short* __restrict__ Cb,
    unsigned short* __restrict__ vT, int K, int cn, int flags)
{
    constexpr int BN   = NF * 64;
    constexpr int SLOT = 32768 + BN * 128;       // bytes: A 32K + B (BN*128)
    __shared__ unsigned char lds[2 * SLOT];

    const int tid  = threadIdx.x;
    const int lane = tid & 63, wid = tid >> 6;
    const int wr = wid >> 2, wc = wid & 3;
    const int fr = lane & 15, fq = lane >> 4;
    const int bm0 = blockIdx.y * 256, bn0 = blockIdx.x * BN;
    const int cxor = (fr & 7) << 4;              // read-side swizzle XOR (bytes)

    // staging: thread t covers row (sweep*64 + t>>3), source col pre-swizzled
    const int srow  = tid >> 3;
    const int scole = ((tid & 7) ^ (srow & 7)) * 8;   // elems
    const unsigned short* Ag = A  + (size_t)(bm0 + srow) * K + scole;
    const unsigned short* Bg = Bm + (size_t)(bn0 + srow) * K + scole;

    f32x4 acc[8][NF];
    #pragma unroll
    for (int i = 0; i < 8; ++i)
        #pragma unroll
        for (int j = 0; j < NF; ++j)
            acc[i][j] = (f32x4){0.f, 0.f, 0.f, 0.f};

    auto ldsA = [&](int slot, int sweep) -> void* {
        return (void*)(lds + slot * SLOT + sweep * 8192 + wid * 1024);
    };
    auto ldsB = [&](int slot, int sweep) -> void* {
        return (void*)(lds + slot * SLOT + 32768 + sweep * 8192 + wid * 1024);
    };
    auto srcA = [&](int kt, int sweep) {
        return Ag + (size_t)sweep * 64 * K + kt * 64;
    };
    auto srcB = [&](int kt, int sweep) {
        return Bg + (size_t)sweep * 64 * K + kt * 64;
    };

    const int nt = K >> 6;

    // Prologue: stage tile 0 -> slot 0 (FIFO order: B..., A0,A2, A1,A3)
    if constexpr (NF == 4) {
        GLDS(srcB(0, 0), ldsB(0, 0)); GLDS(srcB(0, 1), ldsB(0, 1));
        GLDS(srcB(0, 2), ldsB(0, 2)); GLDS(srcB(0, 3), ldsB(0, 3));
    } else {
        GLDS(srcB(0, 0), ldsB(0, 0)); GLDS(srcB(0, 1), ldsB(0, 1));
    }
    GLDS(srcA(0, 0), ldsA(0, 0)); GLDS(srcA(0, 2), ldsA(0, 2));
    GLDS(srcA(0, 1), ldsA(0, 1)); GLDS(srcA(0, 3), ldsA(0, 3));
    asm volatile("s_waitcnt vmcnt(2)" ::: "memory");
    __builtin_amdgcn_s_barrier();

    for (int kt = 0; kt < nt; ++kt) {
        const int slot = kt & 1;
        const unsigned char* sb = lds + slot * SLOT;
        const int ns = slot ^ 1;
        const bool stg = (kt + 1 < nt);
        const int kn = kt + 1;

#define PHASE(P)                                                               \
    {                                                                          \
        constexpr int mh = (P) >> 1, nh = (P) & 1;                             \
        bf16x8 af[4][2], bfr[NF / 2][2];                                       \
        _Pragma("unroll")                                                      \
        for (int mi = 0; mi < 4; ++mi)                                         \
            _Pragma("unroll")                                                  \
            for (int kk = 0; kk < 2; ++kk)                                     \
                af[mi][kk] = *(const bf16x8*)(sb +                             \
                    (wr * 128 + mh * 64 + mi * 16 + fr) * 128 +                \
                    ((kk * 64 + fq * 16) ^ cxor));                             \
        _Pragma("unroll")                                                      \
        for (int ni = 0; ni < NF / 2; ++ni)                                    \
            _Pragma("unroll")                                                  \
            for (int kk = 0; kk < 2; ++kk)                                     \
                bfr[ni][kk] = *(const bf16x8*)(sb + 32768 +                    \
                    (wc * NF * 16 + nh * (NF / 2) * 16 + ni * 16 + fr) * 128 + \
                    ((kk * 64 + fq * 16) ^ cxor));                             \
        if (stg) {                                                             \
            if constexpr (NF == 4) {                                           \
                if ((P) == 0) { GLDS(srcB(kn, 0), ldsB(ns, 0));                \
                                GLDS(srcB(kn, 1), ldsB(ns, 1)); }              \
                if ((P) == 1) { GLDS(srcB(kn, 2), ldsB(ns, 2));                \
                                GLDS(srcB(kn, 3), ldsB(ns, 3)); }              \
                if ((P) == 2) { GLDS(srcA(kn, 0), ldsA(ns, 0));                \
                                GLDS(srcA(kn, 2), ldsA(ns, 2)); }              \
                if ((P) == 3) { GLDS(srcA(kn, 1), ldsA(ns, 1));                \
                                GLDS(srcA(kn, 3), ldsA(ns, 3)); }              \
            } else {                                                           \
                if ((P) == 0) { GLDS(srcB(kn, 0), ldsB(ns, 0));                \
                                GLDS(srcB(kn, 1), ldsB(ns, 1)); }              \
                if ((P) == 1) { GLDS(srcA(kn, 0), ldsA(ns, 0));                \
                                GLDS(srcA(kn, 2), ldsA(ns, 2)); }              \
                if ((P) == 2) { GLDS(srcA(kn, 1), ldsA(ns, 1));                \
                                GLDS(srcA(kn, 3), ldsA(ns, 3)); }              \
            }                                                                  \
        }                                                                      \
        if ((P) == 1) {                                                        \
            if (stg) asm volatile("s_waitcnt vmcnt(4)" ::: "memory");          \
            else     asm volatile("s_waitcnt vmcnt(0)" ::: "memory");          \
        }                                                                      \
        if ((P) == 3 && stg) asm volatile("s_waitcnt vmcnt(2)" ::: "memory");  \
        __builtin_amdgcn_s_barrier();                                          \
        asm volatile("s_waitcnt lgkmcnt(0)" ::: "memory");                     \
        __builtin_amdgcn_s_setprio(1);                                         \
        _Pragma("unroll")                                                      \
        for (int mi = 0; mi < 4; ++mi)                                         \
            _Pragma("unroll")                                                  \
            for (int ni = 0; ni < NF / 2; ++ni) {                              \
                f32x4 c = acc[mh * 4 + mi][nh * (NF / 2) + ni];                \
                c = __builtin_amdgcn_mfma_f32_16x16x32_bf16(                   \
                        af[mi][0], bfr[ni][0], c, 0, 0, 0);                    \
                c = __builtin_amdgcn_mfma_f32_16x16x32_bf16(                   \
                        af[mi][1], bfr[ni][1], c, 0, 0, 0);                    \
                acc[mh * 4 + mi][nh * (NF / 2) + ni] = c;                      \
            }                                                                  \
        __builtin_amdgcn_s_setprio(0);                                         \
        __builtin_amdgcn_s_barrier();                                          \
    }
        PHASE(0) PHASE(1) PHASE(2) PHASE(3)
#undef PHASE
    }

    // Epilogue
    float bj[NF];
    #pragma unroll
    for (int an = 0; an < NF; ++an) bj[an] = 0.f;
    if (flags & 1) {
        #pragma unroll
        for (int an = 0; an < NF; ++an)
            bj[an] = bias[bn0 + wc * NF * 16 + an * 16 + fr];
    }
    bool relu = flags & 2;
    bool qkvm = flags & 4;
    #pragma unroll
    for (int am = 0; am < 8; ++am) {
        int row0 = bm0 + wr * 128 + (am >> 2) * 64 + (am & 3) * 16 + fq * 4;
        #pragma unroll
        for (int an = 0; an < NF; ++an) {
            int col = bn0 + wc * NF * 16 + an * 16 + fr;
            float v[4];
            #pragma unroll
            for (int r = 0; r < 4; ++r) {
                v[r] = acc[am][an][r] + bj[an];
                if (relu) v[r] = fmaxf(v[r], 0.f);
            }
            if (qkvm) {
                if (col < 1024) {          // q|k row-major, stride cn
                    #pragma unroll
                    for (int r = 0; r < 4; ++r)
                        Cb[(size_t)(row0 + r) * cn + col] = f2b(v[r]);
                } else {                   // v -> vT[(b*8+m)*64+d][l]
                    int mm = (col - 1024) >> 6, dd = (col - 1024) & 63;
                    int bb = row0 >> 10, l0 = row0 & 1023;
                    us4 p;
                    p.x = f2b(v[0]); p.y = f2b(v[1]); p.z = f2b(v[2]); p.w = f2b(v[3]);
                    *(us4*)&vT[((size_t)(bb * 8 + mm) * 64 + dd) * 1024 + l0] = p;
                }
            } else {
                #pragma unroll
                for (int r = 0; r < 4; ++r)
                    Cb[(size_t)(row0 + r) * cn + col] = f2b(v[r]);
            }
        }
    }
}

// ---------------------------------------------------------------------------
// MFMA flash attention (unchanged from R5). qk [BL][1024] bf16, vT transposed.
#define KST 72
__global__ __launch_bounds__(256) void attn_mfma_kernel(
    const unsigned short* __restrict__ qk, const unsigned short* __restrict__ vT,
    unsigned short* __restrict__ t)
{
    __shared__ unsigned short Ks[64 * KST];
    __shared__ unsigned short Vs[64 * KST];
    __shared__ unsigned short Pb[4][16 * KST];

    int tid = threadIdx.x;
    int lane = tid & 63, wid = tid >> 6;
    int fr = lane & 15, fq = lane >> 4;
    int b = blockIdx.z, m = blockIdx.y, q0 = blockIdx.x * 64;
    int bq = b * L_;

    size_t qrow = (size_t)(bq + q0 + wid * 16 + fr) * 1024 + m * 64;
    bf16x8 qa[2];
    qa[0] = *(const bf16x8*)&qk[qrow + fq * 8];
    qa[1] = *(const bf16x8*)&qk[qrow + 32 + fq * 8];

    f32x4 oacc[4];
    #pragma unroll
    for (int i = 0; i < 4; ++i) oacc[i] = (f32x4){0.f, 0.f, 0.f, 0.f};
    float lsum[4] = {0.f, 0.f, 0.f, 0.f};

    int srow = tid >> 3;
    int scol = (tid & 7) * 8;
    const unsigned short* kg = qk + (size_t)bq * 1024 + 512 + m * 64 + scol;
    const unsigned short* vg = vT + ((size_t)(b * 8 + m) * 64) * 1024 + scol;
    unsigned short* pw = Pb[wid];

    uint4 k0 = *(const uint4*)&kg[(size_t)(srow) * 1024];
    uint4 k1 = *(const uint4*)&kg[(size_t)(srow + 32) * 1024];
    uint4 v0 = *(const uint4*)&vg[(size_t)(srow) * 1024];
    uint4 v1 = *(const uint4*)&vg[(size_t)(srow + 32) * 1024];

    for (int kt = 0; kt < L_ / 64; ++kt) {
        __syncthreads();
        *(uint4*)&Ks[(srow)      * KST + scol] = k0;
        *(uint4*)&Ks[(srow + 32) * KST + scol] = k1;
        *(uint4*)&Vs[(srow)      * KST + scol] = v0;
        *(uint4*)&Vs[(srow + 32) * KST + scol] = v1;
        __syncthreads();
        if (kt + 1 < L_ / 64) {
            int kb = (kt + 1) * 64;
            k0 = *(const uint4*)&kg[(size_t)(kb + srow) * 1024];
            k1 = *(const uint4*)&kg[(size_t)(kb + srow + 32) * 1024];
            v0 = *(const uint4*)&vg[(size_t)(srow) * 1024 + kb];
            v1 = *(const uint4*)&vg[(size_t)(srow + 32) * 1024 + kb];
        }

        __builtin_amdgcn_s_setprio(1);
        #pragma unroll
        for (int nk = 0; nk < 4; ++nk) {
            bf16x8 kf0 = *(const bf16x8*)&Ks[(nk * 16 + fr) * KST + fq * 8];
            bf16x8 kf1 = *(const bf16x8*)&Ks[(nk * 16 + fr) * KST + 32 + fq * 8];
            f32x4 s = __builtin_amdgcn_mfma_f32_16x16x32_bf16(
                qa[0], kf0, (f32x4){0.f, 0.f, 0.f, 0.f}, 0, 0, 0);
            s = __builtin_amdgcn_mfma_f32_16x16x32_bf16(qa[1], kf1, s, 0, 0, 0);
            #pragma unroll
            for (int r = 0; r < 4; ++r) {
                float p = __expf(s[r] * 0.125f);
                lsum[r] += p;
                pw[(fq * 4 + r) * KST + nk * 16 + fr] = f2b(p);
            }
        }
        bf16x8 pa0 = *(const bf16x8*)&pw[fr * KST + fq * 8];
        bf16x8 pa1 = *(const bf16x8*)&pw[fr * KST + 32 + fq * 8];
        #pragma unroll
        for (int nt = 0; nt < 4; ++nt) {
            bf16x8 vf0 = *(const bf16x8*)&Vs[(nt * 16 + fr) * KST + fq * 8];
            bf16x8 vf1 = *(const bf16x8*)&Vs[(nt * 16 + fr) * KST + 32 + fq * 8];
            oacc[nt] = __builtin_amdgcn_mfma_f32_16x16x32_bf16(pa0, vf0, oacc[nt], 0, 0, 0);
            oacc[nt] = __builtin_amdgcn_mfma_f32_16x16x32_bf16(pa1, vf1, oacc[nt], 0, 0, 0);
        }
        __builtin_amdgcn_s_setprio(0);
    }

    #pragma unroll
    for (int r = 0; r < 4; ++r) {
        float s = lsum[r];
        s += __shfl_xor(s, 1); s += __shfl_xor(s, 2);
        s += __shfl_xor(s, 4); s += __shfl_xor(s, 8);
        lsum[r] = 1.f / s;
    }
    #pragma unroll
    for (int r = 0; r < 4; ++r) {
        size_t orow = (size_t)(bq + q0 + wid * 16 + fq * 4 + r) * DH_ + m * 64;
        #pragma unroll
        for (int nt = 0; nt < 4; ++nt)
            t[orow + nt * 16 + fr] = f2b(oacc[nt][r] * lsum[r]);
    }
}

// ---------------------------------------------------------------------------
__global__ __launch_bounds__(256) void bn_stats_kernel(
    const unsigned short* __restrict__ a, const unsigned short* __restrict__ b,
    float* __restrict__ stats)
{
    int l = blockIdx.x, tid = threadIdx.x;
    float s = 0.f, s2 = 0.f;
    #pragma unroll
    for (int u = tid; u < 1024; u += 256) {
        int bb = u >> 6, dg = (u & 63) * 8;
        size_t off = ((size_t)bb * L_ + l) * DH_ + dg;
        us8 va = *(const us8*)&a[off];
        us8 vb = *(const us8*)&b[off];
        #pragma unroll
        for (int j = 0; j < 8; ++j) {
            float z = b2f(va[j]) + b2f(vb[j]);
            s += z;
            s2 = fmaf(z, z, s2);
        }
    }
    #pragma unroll
    for (int off = 32; off > 0; off >>= 1) {
        s  += __shfl_down(s, off);
        s2 += __shfl_down(s2, off);
    }
    __shared__ float red[8];
    int w = tid >> 6;
    if ((tid & 63) == 0) { red[w] = s; red[4 + w] = s2; }
    __syncthreads();
    if (tid == 0) {
        float S  = red[0] + red[1] + red[2] + red[3];
        float S2 = red[4] + red[5] + red[6] + red[7];
        float mu  = S * (1.f / 8192.f);
        float var = S2 * (1.f / 8192.f) - mu * mu;
        stats[l]      = mu;
        stats[L_ + l] = rsqrtf(var + 1e-5f);
    }
}

__global__ __launch_bounds__(256) void bn_apply_kernel(
    const unsigned short* __restrict__ a, const unsigned short* __restrict__ b,
    const float* __restrict__ stats, const float* __restrict__ w,
    const float* __restrict__ bias, unsigned short* __restrict__ outb,
    float* __restrict__ outf)
{
    int idx = blockIdx.x * 256 + threadIdx.x;   // BL_*DH_/8
    int bl = idx >> 6;
    int d0 = (idx & 63) * 8;
    int l  = bl & (L_ - 1);
    float mu = stats[l], rs = stats[L_ + l];
    size_t off = (size_t)bl * DH_ + d0;
    us8 va = *(const us8*)&a[off];
    us8 vb = *(const us8*)&b[off];
    float o[8];
    #pragma unroll
    for (int j = 0; j < 8; ++j) {
        float z = b2f(va[j]) + b2f(vb[j]);
        o[j] = fmaf(w[d0 + j], (z - mu) * rs, bias[d0 + j]);
    }
    if (outb) {
        us8 ob;
        #pragma unroll
        for (int j = 0; j < 8; ++j) ob[j] = f2b(o[j]);
        *(us8*)&outb[off] = ob;
    }
    if (outf) {
        float4 o0 = {o[0], o[1], o[2], o[3]};
        float4 o1 = {o[4], o[5], o[6], o[7]};
        *(float4*)&outf[off]     = o0;
        *(float4*)&outf[off + 4] = o1;
    }
}

// ---------------------------------------------------------------------------
extern "C" void kernel_launch(void* const* d_in, const int* in_sizes, int n_in,
                              void* d_out, int out_size, void* d_ws, size_t ws_size,
                              hipStream_t stream)
{
    const float* x    = (const float*)d_in[0];
    const float* Wh   = (const float*)d_in[1];
    const float* bh   = (const float*)d_in[2];
    const float* Wq   = (const float*)d_in[3];
    const float* Wk   = (const float*)d_in[4];
    const float* Wv   = (const float*)d_in[5];
    const float* Wo   = (const float*)d_in[6];
    const float* wbn  = (const float*)d_in[7];
    const float* bbn  = (const float*)d_in[8];
    const float* Wff0 = (const float*)d_in[9];
    const float* bff0 = (const float*)d_in[10];
    const float* Wff1 = (const float*)d_in[11];
    const float* bff1 = (const float*)d_in[12];
    float* out = (float*)d_out;

    // Workspace (~146 MB), all activations bf16 (layout as R5):
    //   st 8KB | hb 16MB | qkkb 32MB | vTb 16MB | tb 16MB | mhab 16MB
    //   hbnb 16MB | ffob 16MB | weights 18MB;  ffmb aliases qkkb+vTb+tb (64MB)
    float* st = (float*)d_ws;
    unsigned short* hb    = (unsigned short*)(st + 2048);
    unsigned short* qkkb  = hb + (size_t)BL_ * DH_;
    unsigned short* vTb   = qkkb + (size_t)BL_ * 1024;
    unsigned short* tb    = vTb + (size_t)BL_ * DH_;
    unsigned short* mhab  = tb + (size_t)BL_ * DH_;
    unsigned short* hbnb  = mhab + (size_t)BL_ * DH_;
    unsigned short* ffob  = hbnb + (size_t)BL_ * DH_;
    unsigned short* wqkvb3 = ffob + (size_t)BL_ * DH_;
    unsigned short* wob3   = wqkvb3 + QKV_T;
    unsigned short* wff0b3 = wob3 + WO_T;
    unsigned short* wff1b3 = wff0b3 + FF_T;
    unsigned short* ffmb  = qkkb;    // alias

    wprep_kernel<<<(QKV_T + WO_T + 2 * FF_T) / 1024, 256, 0, stream>>>(
        Wq, Wk, Wv, Wo, Wff0, Wff1, wqkvb3, wob3, wff0b3, wff1b3);
    embed_kernel<<<BL_ * DH_ / 4 / 256, 256, 0, stream>>>(x, Wh, bh, hb);

    dim3 gqkv(1536 / 256, BL_ / 256);   // NF=4
    dim3 gwo(512 / 128, BL_ / 256);     // NF=2
    dim3 gff0(2048 / 256, BL_ / 256);   // NF=4
    dim3 gff1(512 / 128, BL_ / 256);    // NF=2
    dim3 gattn(L_ / 64, M_, B_);
    int gbn = BL_ * DH_ / 8 / 256;

    for (int n = 0; n < NL_; ++n) {
        const unsigned short* wqkvb = wqkvb3 + (size_t)n * 786432;
        const unsigned short* wob   = wob3   + (size_t)n * 262144;
        const unsigned short* wff0b = wff0b3 + (size_t)n * 1048576;
        const unsigned short* wff1b = wff1b3 + (size_t)n * 1048576;
        const float* wbn_n  = wbn  + (size_t)n * DH_;
        const float* bbn_n  = bbn  + (size_t)n * DH_;
        const float* bff0_n = bff0 + (size_t)n * DFF_;
        const float* bff1_n = bff1 + (size_t)n * DH_;
        bool last = (n == NL_ - 1);

        // qkv: q|k -> qkkb [BL][1024], v -> vTb transposed
        gemm8p_kernel<4><<<gqkv, 512, 0, stream>>>(hb, wqkvb, nullptr,
            qkkb, vTb, DH_, 1024, 4);
        // t = softmax(q k^T / 8) v -> tb
        attn_mfma_kernel<<<gattn, 256, 0, stream>>>(qkkb, vTb, tb);
        // h_mha = t @ wob^T -> mhab
        gemm8p_kernel<2><<<gwo, 512, 0, stream>>>(tb, wob, nullptr,
            mhab, nullptr, DH_, DH_, 0);
        // h_bn = w*BN(h + h_mha) + b -> hbnb
        bn_stats_kernel<<<L_, 256, 0, stream>>>(hb, mhab, st);
        bn_apply_kernel<<<gbn, 256, 0, stream>>>(hb, mhab, st, wbn_n, bbn_n,
            hbnb, nullptr);
        // ff = relu(h_bn @ Wff0^T + bff0) @ Wff1^T + bff1 -> ffob
        gemm8p_kernel<4><<<gff0, 512, 0, stream>>>(hbnb, wff0b, bff0_n,
            ffmb, nullptr, DH_, DFF_, 1 | 2);
        gemm8p_kernel<2><<<gff1, 512, 0, stream>>>(ffmb, wff1b, bff1_n,
            ffob, nullptr, DFF_, DH_, 1);
        // h = w*BN(h_bn + ff) + b  (final layer -> fp32 d_out)
        bn_stats_kernel<<<L_, 256, 0, stream>>>(hbnb, ffob, st);
        bn_apply_kernel<<<gbn, 256, 0, stream>>>(hbnb, ffob, st, wbn_n, bbn_n,
            last ? nullptr : hb, last ? out : nullptr);
    }
}

// Round 8
// 776.231 us; speedup vs baseline: 10.8522x; 1.0383x over previous
//
#include <hip/hip_runtime.h>
#include <hip/hip_bf16.h>
#include <math.h>

// Problem constants (Encoder_24816321036413)
#define B_   16
#define L_   1024
#define BL_  16384      // B_*L_
#define DH_  512
#define DFF_ 2048
#define NL_  3
#define M_   8
#define DK_  64

typedef __attribute__((ext_vector_type(8))) short bf16x8;
typedef __attribute__((ext_vector_type(4))) float f32x4;
typedef __attribute__((ext_vector_type(4))) unsigned short us4;
typedef __attribute__((ext_vector_type(8))) unsigned short us8;

__device__ __forceinline__ unsigned short f2b(float x) {
    __hip_bfloat16 h = __float2bfloat16(x);   // RNE
    return *(unsigned short*)&h;
}
__device__ __forceinline__ float b2f(unsigned short u) {
    unsigned int v = ((unsigned int)u) << 16;
    return __builtin_bit_cast(float, v);
}

#define GLDS(g, l) __builtin_amdgcn_global_load_lds( \
        (const __attribute__((address_space(1))) unsigned int*)(const void*)(g), \
        (__attribute__((address_space(3))) unsigned int*)(void*)(l), 16, 0, 0)

// ---------------------------------------------------------------------------
// One-shot weight prep (all layers): QKV fuse, Wo repack, FF0/FF1 cvt -> bf16
#define QKV_T 2359296   // 3 layers * 3 mats * 262144
#define WO_T  786432
#define FF_T  3145728   // 3 * 2048*512
__global__ __launch_bounds__(256) void wprep_kernel(
    const float* __restrict__ Wq, const float* __restrict__ Wk,
    const float* __restrict__ Wv, const float* __restrict__ Wo,
    const float* __restrict__ Wff0, const float* __restrict__ Wff1,
    unsigned short* __restrict__ wqkvb3, unsigned short* __restrict__ wob3,
    unsigned short* __restrict__ wff0b3, unsigned short* __restrict__ wff1b3)
{
    int i4 = (blockIdx.x * 256 + threadIdx.x) * 4;
    const float* src;
    unsigned short* dst;
    if (i4 < QKV_T) {
        int n = i4 / 786432, r = i4 % 786432;
        if (r < 262144)      src = Wq + (size_t)n * 262144 + r;
        else if (r < 524288) src = Wk + (size_t)n * 262144 + r - 262144;
        else                 src = Wv + (size_t)n * 262144 + r - 524288;
        dst = wqkvb3 + i4;
    } else if (i4 < QKV_T + WO_T) {
        int i = i4 - QKV_T;
        int n = i / 262144, r = i % 262144;
        int d = r >> 9, mv = r & 511, mm = mv >> 6, vv = mv & 63;
        src = Wo + (size_t)n * 262144 + ((size_t)mm * 512 + d) * 64 + vv;
        dst = wob3 + i;
    } else if (i4 < QKV_T + WO_T + FF_T) {
        int i = i4 - QKV_T - WO_T;
        src = Wff0 + i;
        dst = wff0b3 + i;
    } else {
        int i = i4 - QKV_T - WO_T - FF_T;
        src = Wff1 + i;
        dst = wff1b3 + i;
    }
    float4 v = *(const float4*)src;
    us4 o;
    o.x = f2b(v.x); o.y = f2b(v.y); o.z = f2b(v.z); o.w = f2b(v.w);
    *(us4*)dst = o;
}

// ---------------------------------------------------------------------------
__global__ __launch_bounds__(256) void embed_kernel(
    const float* __restrict__ x, const float* __restrict__ Wh,
    const float* __restrict__ bh, unsigned short* __restrict__ hb)
{
    int idx = blockIdx.x * 256 + threadIdx.x;   // BL_*DH_/4
    int bl = idx >> 7;
    int e0 = (idx & 127) * 4;
    float x0 = x[bl * 2], x1 = x[bl * 2 + 1];
    us4 o;
    #pragma unroll
    for (int r = 0; r < 4; ++r) {
        int e = e0 + r;
        float v = fmaf(x0, Wh[e * 2], fmaf(x1, Wh[e * 2 + 1], bh[e]));
        ((unsigned short*)&o)[r] = f2b(v);
    }
    *(us4*)&hb[(size_t)bl * DH_ + e0] = o;
}

// ---------------------------------------------------------------------------
// 8-phase 256xBN bf16 GEMM-NT (HK schedule port; see R6 notes).
// NF=4 -> BN=256, NF=2 -> BN=128.  512 thr = 8 waves (2M x 4N), BK=64, dbuf.
// Wait ledger: vmcnt(2) prologue / vmcnt(4) end-ph1 / vmcnt(2) end-ph3, all
// before an s_barrier (cross-wave visibility).  T2 swizzle both-sides.
// flags: bit0 bias, bit1 relu, bit2 qkv-mode (col<1024 -> Cb stride cn with
//        q-cols (<512) pre-scaled by 0.125*log2e for exp2-softmax;
//        col>=1024 -> vT[(b*8+m)*64+d][l] transposed scatter).
template<int NF>
__global__ __launch_bounds__(512, 2) void gemm8p_kernel(
    const unsigned short* __restrict__ A, const unsigned short* __restrict__ Bm,
    const float* __restrict__ bias, unsigned short* __restrict__ Cb,
    unsigned short* __restrict__ vT, int K, int cn, int flags)
{
    constexpr int BN   = NF * 64;
    constexpr int SLOT = 32768 + BN * 128;       // bytes: A 32K + B (BN*128)
    __shared__ unsigned char lds[2 * SLOT];

    const int tid  = threadIdx.x;
    const int lane = tid & 63, wid = tid >> 6;
    const int wr = wid >> 2, wc = wid & 3;
    const int fr = lane & 15, fq = lane >> 4;
    const int bm0 = blockIdx.y * 256, bn0 = blockIdx.x * BN;
    const int cxor = (fr & 7) << 4;              // read-side swizzle XOR (bytes)

    const int srow  = tid >> 3;
    const int scole = ((tid & 7) ^ (srow & 7)) * 8;   // pre-swizzled source col
    const unsigned short* Ag = A  + (size_t)(bm0 + srow) * K + scole;
    const unsigned short* Bg = Bm + (size_t)(bn0 + srow) * K + scole;

    f32x4 acc[8][NF];
    #pragma unroll
    for (int i = 0; i < 8; ++i)
        #pragma unroll
        for (int j = 0; j < NF; ++j)
            acc[i][j] = (f32x4){0.f, 0.f, 0.f, 0.f};

    auto ldsA = [&](int slot, int sweep) -> void* {
        return (void*)(lds + slot * SLOT + sweep * 8192 + wid * 1024);
    };
    auto ldsB = [&](int slot, int sweep) -> void* {
        return (void*)(lds + slot * SLOT + 32768 + sweep * 8192 + wid * 1024);
    };
    auto srcA = [&](int kt, int sweep) {
        return Ag + (size_t)sweep * 64 * K + kt * 64;
    };
    auto srcB = [&](int kt, int sweep) {
        return Bg + (size_t)sweep * 64 * K + kt * 64;
    };

    const int nt = K >> 6;

    if constexpr (NF == 4) {
        GLDS(srcB(0, 0), ldsB(0, 0)); GLDS(srcB(0, 1), ldsB(0, 1));
        GLDS(srcB(0, 2), ldsB(0, 2)); GLDS(srcB(0, 3), ldsB(0, 3));
    } else {
        GLDS(srcB(0, 0), ldsB(0, 0)); GLDS(srcB(0, 1), ldsB(0, 1));
    }
    GLDS(srcA(0, 0), ldsA(0, 0)); GLDS(srcA(0, 2), ldsA(0, 2));
    GLDS(srcA(0, 1), ldsA(0, 1)); GLDS(srcA(0, 3), ldsA(0, 3));
    asm volatile("s_waitcnt vmcnt(2)" ::: "memory");
    __builtin_amdgcn_s_barrier();

    for (int kt = 0; kt < nt; ++kt) {
        const int slot = kt & 1;
        const unsigned char* sb = lds + slot * SLOT;
        const int ns = slot ^ 1;
        const bool stg = (kt + 1 < nt);
        const int kn = kt + 1;

#define PHASE(P)                                                               \
    {                                                                          \
        constexpr int mh = (P) >> 1, nh = (P) & 1;                             \
        bf16x8 af[4][2], bfr[NF / 2][2];                                       \
        _Pragma("unroll")                                                      \
        for (int mi = 0; mi < 4; ++mi)                                         \
            _Pragma("unroll")                                                  \
            for (int kk = 0; kk < 2; ++kk)                                     \
                af[mi][kk] = *(const bf16x8*)(sb +                             \
                    (wr * 128 + mh * 64 + mi * 16 + fr) * 128 +                \
                    ((kk * 64 + fq * 16) ^ cxor));                             \
        _Pragma("unroll")                                                      \
        for (int ni = 0; ni < NF / 2; ++ni)                                    \
            _Pragma("unroll")                                                  \
            for (int kk = 0; kk < 2; ++kk)                                     \
                bfr[ni][kk] = *(const bf16x8*)(sb + 32768 +                    \
                    (wc * NF * 16 + nh * (NF / 2) * 16 + ni * 16 + fr) * 128 + \
                    ((kk * 64 + fq * 16) ^ cxor));                             \
        if (stg) {                                                             \
            if constexpr (NF == 4) {                                           \
                if ((P) == 0) { GLDS(srcB(kn, 0), ldsB(ns, 0));                \
                                GLDS(srcB(kn, 1), ldsB(ns, 1)); }              \
                if ((P) == 1) { GLDS(srcB(kn, 2), ldsB(ns, 2));                \
                                GLDS(srcB(kn, 3), ldsB(ns, 3)); }              \
                if ((P) == 2) { GLDS(srcA(kn, 0), ldsA(ns, 0));                \
                                GLDS(srcA(kn, 2), ldsA(ns, 2)); }              \
                if ((P) == 3) { GLDS(srcA(kn, 1), ldsA(ns, 1));                \
                                GLDS(srcA(kn, 3), ldsA(ns, 3)); }              \
            } else {                                                           \
                if ((P) == 0) { GLDS(srcB(kn, 0), ldsB(ns, 0));                \
                                GLDS(srcB(kn, 1), ldsB(ns, 1)); }              \
                if ((P) == 1) { GLDS(srcA(kn, 0), ldsA(ns, 0));                \
                                GLDS(srcA(kn, 2), ldsA(ns, 2)); }              \
                if ((P) == 2) { GLDS(srcA(kn, 1), ldsA(ns, 1));                \
                                GLDS(srcA(kn, 3), ldsA(ns, 3)); }              \
            }                                                                  \
        }                                                                      \
        if ((P) == 1) {                                                        \
            if (stg) asm volatile("s_waitcnt vmcnt(4)" ::: "memory");          \
            else     asm volatile("s_waitcnt vmcnt(0)" ::: "memory");          \
        }                                                                      \
        if ((P) == 3 && stg) asm volatile("s_waitcnt vmcnt(2)" ::: "memory");  \
        __builtin_amdgcn_s_barrier();                                          \
        asm volatile("s_waitcnt lgkmcnt(0)" ::: "memory");                     \
        __builtin_amdgcn_s_setprio(1);                                         \
        _Pragma("unroll")                                                      \
        for (int mi = 0; mi < 4; ++mi)                                         \
            _Pragma("unroll")                                                  \
            for (int ni = 0; ni < NF / 2; ++ni) {                              \
                f32x4 c = acc[mh * 4 + mi][nh * (NF / 2) + ni];                \
                c = __builtin_amdgcn_mfma_f32_16x16x32_bf16(                   \
                        af[mi][0], bfr[ni][0], c, 0, 0, 0);                    \
                c = __builtin_amdgcn_mfma_f32_16x16x32_bf16(                   \
                        af[mi][1], bfr[ni][1], c, 0, 0, 0);                    \
                acc[mh * 4 + mi][nh * (NF / 2) + ni] = c;                      \
            }                                                                  \
        __builtin_amdgcn_s_setprio(0);                                         \
        __builtin_amdgcn_s_barrier();                                          \
    }
        PHASE(0) PHASE(1) PHASE(2) PHASE(3)
#undef PHASE
    }

    // Epilogue
    float bj[NF];
    #pragma unroll
    for (int an = 0; an < NF; ++an) bj[an] = 0.f;
    if (flags & 1) {
        #pragma unroll
        for (int an = 0; an < NF; ++an)
            bj[an] = bias[bn0 + wc * NF * 16 + an * 16 + fr];
    }
    bool relu = flags & 2;
    bool qkvm = flags & 4;
    #pragma unroll
    for (int am = 0; am < 8; ++am) {
        int row0 = bm0 + wr * 128 + (am >> 2) * 64 + (am & 3) * 16 + fq * 4;
        #pragma unroll
        for (int an = 0; an < NF; ++an) {
            int col = bn0 + wc * NF * 16 + an * 16 + fr;
            float v[4];
            #pragma unroll
            for (int r = 0; r < 4; ++r) {
                v[r] = acc[am][an][r] + bj[an];
                if (relu) v[r] = fmaxf(v[r], 0.f);
            }
            if (qkvm) {
                if (col < 1024) {          // q|k row-major; q pre-scaled for exp2
                    float sc = (col < 512) ? 0.1803368801111244f : 1.0f;
                    #pragma unroll
                    for (int r = 0; r < 4; ++r)
                        Cb[(size_t)(row0 + r) * cn + col] = f2b(v[r] * sc);
                } else {                   // v -> vT[(b*8+m)*64+d][l]
                    int mm = (col - 1024) >> 6, dd = (col - 1024) & 63;
                    int bb = row0 >> 10, l0 = row0 & 1023;
                    us4 p;
                    p.x = f2b(v[0]); p.y = f2b(v[1]); p.z = f2b(v[2]); p.w = f2b(v[3]);
                    *(us4*)&vT[((size_t)(bb * 8 + mm) * 64 + dd) * 1024 + l0] = p;
                }
            } else {
                #pragma unroll
                for (int r = 0; r < 4; ++r)
                    Cb[(size_t)(row0 + r) * cn + col] = f2b(v[r]);
            }
        }
    }
}

// ---------------------------------------------------------------------------
// MFMA flash attention v2: 4 waves x 32 q-rows = 128 q-rows/WG.
// qk [BL][1024] bf16 (q pre-scaled by 0.125*log2e -> softmax = exp2f, which
// lowers to v_exp_f32 as compiler-visible IR: MFMA->VALU hazards handled.
// R7's inline-asm v_exp_f32 consumer of the MFMA acc got NO hazard padding
// -> stale reads -> absmax 3.2).  vT [(b*8+m)*64+d][1024].  XCD-swizzled
// 1D grid 1024: all 8 q-blocks of a (b,m) pair on one XCD (256KB K/V in L2).
#define KST 72
__global__ __launch_bounds__(256, 4) void attn_mfma_kernel(
    const unsigned short* __restrict__ qk, const unsigned short* __restrict__ vT,
    unsigned short* __restrict__ t)
{
    __shared__ unsigned short Ks[64 * KST];    // [key][d]
    __shared__ unsigned short Vs[64 * KST];    // [d][key]
    __shared__ unsigned short Pb[4][32 * KST]; // per-wave [q][key]

    int tid = threadIdx.x;
    int lane = tid & 63, wid = tid >> 6;
    int fr = lane & 15, fq = lane >> 4;
    // bijective bit-split: xcd=j&7, qblk=(j>>3)&7, pairhi=j>>6
    int j = blockIdx.x;
    int pair = (j & 7) * 16 + (j >> 6);        // 0..127 = b*8+m
    int q0 = ((j >> 3) & 7) * 128;
    int b = pair >> 3, m = pair & 7;
    int bq = b * L_;

    size_t qbase = (size_t)(bq + q0 + wid * 32) * 1024 + m * 64;
    bf16x8 qa[2][2];
    #pragma unroll
    for (int qh = 0; qh < 2; ++qh) {
        qa[qh][0] = *(const bf16x8*)&qk[qbase + (size_t)(qh * 16 + fr) * 1024 + fq * 8];
        qa[qh][1] = *(const bf16x8*)&qk[qbase + (size_t)(qh * 16 + fr) * 1024 + 32 + fq * 8];
    }

    f32x4 oacc[2][4];
    #pragma unroll
    for (int qh = 0; qh < 2; ++qh)
        #pragma unroll
        for (int i = 0; i < 4; ++i) oacc[qh][i] = (f32x4){0.f, 0.f, 0.f, 0.f};
    float lsum[2][4] = {{0.f, 0.f, 0.f, 0.f}, {0.f, 0.f, 0.f, 0.f}};

    int srow = tid >> 3;
    int scol = (tid & 7) * 8;
    const unsigned short* kg = qk + (size_t)bq * 1024 + 512 + m * 64 + scol;
    const unsigned short* vg = vT + ((size_t)pair * 64) * 1024 + scol;
    unsigned short* pw = Pb[wid];

    // prefetch tile 0
    uint4 k0 = *(const uint4*)&kg[(size_t)(srow) * 1024];
    uint4 k1 = *(const uint4*)&kg[(size_t)(srow + 32) * 1024];
    uint4 v0 = *(const uint4*)&vg[(size_t)(srow) * 1024];
    uint4 v1 = *(const uint4*)&vg[(size_t)(srow + 32) * 1024];

    for (int kt = 0; kt < L_ / 64; ++kt) {
        __syncthreads();                       // prev tile's reads done
        *(uint4*)&Ks[(srow)      * KST + scol] = k0;
        *(uint4*)&Ks[(srow + 32) * KST + scol] = k1;
        *(uint4*)&Vs[(srow)      * KST + scol] = v0;
        *(uint4*)&Vs[(srow + 32) * KST + scol] = v1;
        __syncthreads();                       // tile staged
        if (kt + 1 < L_ / 64) {                // prefetch next under compute
            int kb = (kt + 1) * 64;
            k0 = *(const uint4*)&kg[(size_t)(kb + srow) * 1024];
            k1 = *(const uint4*)&kg[(size_t)(kb + srow + 32) * 1024];
            v0 = *(const uint4*)&vg[(size_t)(srow) * 1024 + kb];
            v1 = *(const uint4*)&vg[(size_t)(srow + 32) * 1024 + kb];
        }

        __builtin_amdgcn_s_setprio(1);
        // lane holds S[q=qh*16+fq*4+r][key=nk*16+fr]; p = 2^s
        #pragma unroll
        for (int nk = 0; nk < 4; ++nk) {
            bf16x8 kf0 = *(const bf16x8*)&Ks[(nk * 16 + fr) * KST + fq * 8];
            bf16x8 kf1 = *(const bf16x8*)&Ks[(nk * 16 + fr) * KST + 32 + fq * 8];
            #pragma unroll
            for (int qh = 0; qh < 2; ++qh) {
                f32x4 s = __builtin_amdgcn_mfma_f32_16x16x32_bf16(
                    qa[qh][0], kf0, (f32x4){0.f, 0.f, 0.f, 0.f}, 0, 0, 0);
                s = __builtin_amdgcn_mfma_f32_16x16x32_bf16(qa[qh][1], kf1, s, 0, 0, 0);
                #pragma unroll
                for (int r = 0; r < 4; ++r) {
                    float p = exp2f(s[r]);     // v_exp_f32, hazard-safe
                    lsum[qh][r] += p;
                    pw[(qh * 16 + fq * 4 + r) * KST + nk * 16 + fr] = f2b(p);
                }
            }
        }
        // PV: A = P[32][64] (row=q), B = V via Vs rows (col=d)
        bf16x8 pa[2][2];
        #pragma unroll
        for (int qh = 0; qh < 2; ++qh) {
            pa[qh][0] = *(const bf16x8*)&pw[(qh * 16 + fr) * KST + fq * 8];
            pa[qh][1] = *(const bf16x8*)&pw[(qh * 16 + fr) * KST + 32 + fq * 8];
        }
        #pragma unroll
        for (int nt = 0; nt < 4; ++nt) {
            bf16x8 vf0 = *(const bf16x8*)&Vs[(nt * 16 + fr) * KST + fq * 8];
            bf16x8 vf1 = *(const bf16x8*)&Vs[(nt * 16 + fr) * KST + 32 + fq * 8];
            #pragma unroll
            for (int qh = 0; qh < 2; ++qh) {
                oacc[qh][nt] = __builtin_amdgcn_mfma_f32_16x16x32_bf16(
                    pa[qh][0], vf0, oacc[qh][nt], 0, 0, 0);
                oacc[qh][nt] = __builtin_amdgcn_mfma_f32_16x16x32_bf16(
                    pa[qh][1], vf1, oacc[qh][nt], 0, 0, 0);
            }
        }
        __builtin_amdgcn_s_setprio(0);
    }

    // denominators: reduce over the 16 fr-lanes of each fq group
    #pragma unroll
    for (int qh = 0; qh < 2; ++qh)
        #pragma unroll
        for (int r = 0; r < 4; ++r) {
            float s = lsum[qh][r];
            s += __shfl_xor(s, 1); s += __shfl_xor(s, 2);
            s += __shfl_xor(s, 4); s += __shfl_xor(s, 8);
            lsum[qh][r] = 1.f / s;
        }
    #pragma unroll
    for (int qh = 0; qh < 2; ++qh)
        #pragma unroll
        for (int r = 0; r < 4; ++r) {
            size_t orow = (size_t)(bq + q0 + wid * 32 + qh * 16 + fq * 4 + r) * DH_ + m * 64;
            #pragma unroll
            for (int nt = 0; nt < 4; ++nt)
                t[orow + nt * 16 + fr] = f2b(oacc[qh][nt][r] * lsum[qh][r]);
        }
}

// ---------------------------------------------------------------------------
__global__ __launch_bounds__(256) void bn_stats_kernel(
    const unsigned short* __restrict__ a, const unsigned short* __restrict__ b,
    float* __restrict__ stats)
{
    int l = blockIdx.x, tid = threadIdx.x;
    float s = 0.f, s2 = 0.f;
    #pragma unroll
    for (int u = tid; u < 1024; u += 256) {
        int bb = u >> 6, dg = (u & 63) * 8;
        size_t off = ((size_t)bb * L_ + l) * DH_ + dg;
        us8 va = *(const us8*)&a[off];
        us8 vb = *(const us8*)&b[off];
        #pragma unroll
        for (int j = 0; j < 8; ++j) {
            float z = b2f(va[j]) + b2f(vb[j]);
            s += z;
            s2 = fmaf(z, z, s2);
        }
    }
    #pragma unroll
    for (int off = 32; off > 0; off >>= 1) {
        s  += __shfl_down(s, off);
        s2 += __shfl_down(s2, off);
    }
    __shared__ float red[8];
    int w = tid >> 6;
    if ((tid & 63) == 0) { red[w] = s; red[4 + w] = s2; }
    __syncthreads();
    if (tid == 0) {
        float S  = red[0] + red[1] + red[2] + red[3];
        float S2 = red[4] + red[5] + red[6] + red[7];
        float mu  = S * (1.f / 8192.f);
        float var = S2 * (1.f / 8192.f) - mu * mu;
        stats[l]      = mu;
        stats[L_ + l] = rsqrtf(var + 1e-5f);
    }
}

__global__ __launch_bounds__(256) void bn_apply_kernel(
    const unsigned short* __restrict__ a, const unsigned short* __restrict__ b,
    const float* __restrict__ stats, const float* __restrict__ w,
    const float* __restrict__ bias, unsigned short* __restrict__ outb,
    float* __restrict__ outf)
{
    int idx = blockIdx.x * 256 + threadIdx.x;   // BL_*DH_/8
    int bl = idx >> 6;
    int d0 = (idx & 63) * 8;
    int l  = bl & (L_ - 1);
    float mu = stats[l], rs = stats[L_ + l];
    size_t off = (size_t)bl * DH_ + d0;
    us8 va = *(const us8*)&a[off];
    us8 vb = *(const us8*)&b[off];
    float o[8];
    #pragma unroll
    for (int j = 0; j < 8; ++j) {
        float z = b2f(va[j]) + b2f(vb[j]);
        o[j] = fmaf(w[d0 + j], (z - mu) * rs, bias[d0 + j]);
    }
    if (outb) {
        us8 ob;
        #pragma unroll
        for (int j = 0; j < 8; ++j) ob[j] = f2b(o[j]);
        *(us8*)&outb[off] = ob;
    }
    if (outf) {
        float4 o0 = {o[0], o[1], o[2], o[3]};
        float4 o1 = {o[4], o[5], o[6], o[7]};
        *(float4*)&outf[off]     = o0;
        *(float4*)&outf[off + 4] = o1;
    }
}

// ---------------------------------------------------------------------------
extern "C" void kernel_launch(void* const* d_in, const int* in_sizes, int n_in,
                              void* d_out, int out_size, void* d_ws, size_t ws_size,
                              hipStream_t stream)
{
    const float* x    = (const float*)d_in[0];
    const float* Wh   = (const float*)d_in[1];
    const float* bh   = (const float*)d_in[2];
    const float* Wq   = (const float*)d_in[3];
    const float* Wk   = (const float*)d_in[4];
    const float* Wv   = (const float*)d_in[5];
    const float* Wo   = (const float*)d_in[6];
    const float* wbn  = (const float*)d_in[7];
    const float* bbn  = (const float*)d_in[8];
    const float* Wff0 = (const float*)d_in[9];
    const float* bff0 = (const float*)d_in[10];
    const float* Wff1 = (const float*)d_in[11];
    const float* bff1 = (const float*)d_in[12];
    float* out = (float*)d_out;

    // Workspace (~146 MB), all activations bf16 (layout as R5/R6)
    float* st = (float*)d_ws;
    unsigned short* hb    = (unsigned short*)(st + 2048);
    unsigned short* qkkb  = hb + (size_t)BL_ * DH_;
    unsigned short* vTb   = qkkb + (size_t)BL_ * 1024;
    unsigned short* tb    = vTb + (size_t)BL_ * DH_;
    unsigned short* mhab  = tb + (size_t)BL_ * DH_;
    unsigned short* hbnb  = mhab + (size_t)BL_ * DH_;
    unsigned short* ffob  = hbnb + (size_t)BL_ * DH_;
    unsigned short* wqkvb3 = ffob + (size_t)BL_ * DH_;
    unsigned short* wob3   = wqkvb3 + QKV_T;
    unsigned short* wff0b3 = wob3 + WO_T;
    unsigned short* wff1b3 = wff0b3 + FF_T;
    unsigned short* ffmb  = qkkb;    // alias (qkkb+vTb+tb = 64MB, dead at FF)

    wprep_kernel<<<(QKV_T + WO_T + 2 * FF_T) / 1024, 256, 0, stream>>>(
        Wq, Wk, Wv, Wo, Wff0, Wff1, wqkvb3, wob3, wff0b3, wff1b3);
    embed_kernel<<<BL_ * DH_ / 4 / 256, 256, 0, stream>>>(x, Wh, bh, hb);

    dim3 gqkv(1536 / 128, BL_ / 256);   // NF=2: 768 WGs = 3 exact rounds
    dim3 gwo(512 / 128, BL_ / 256);     // NF=2: 256
    dim3 gff0(2048 / 256, BL_ / 256);   // NF=4: 512 = 2 exact rounds
    dim3 gff1(512 / 128, BL_ / 256);    // NF=2: 256
    int gbn = BL_ * DH_ / 8 / 256;

    for (int n = 0; n < NL_; ++n) {
        const unsigned short* wqkvb = wqkvb3 + (size_t)n * 786432;
        const unsigned short* wob   = wob3   + (size_t)n * 262144;
        const unsigned short* wff0b = wff0b3 + (size_t)n * 1048576;
        const unsigned short* wff1b = wff1b3 + (size_t)n * 1048576;
        const float* wbn_n  = wbn  + (size_t)n * DH_;
        const float* bbn_n  = bbn  + (size_t)n * DH_;
        const float* bff0_n = bff0 + (size_t)n * DFF_;
        const float* bff1_n = bff1 + (size_t)n * DH_;
        bool last = (n == NL_ - 1);

        // qkv: q|k -> qkkb [BL][1024] (q pre-scaled), v -> vTb transposed
        gemm8p_kernel<2><<<gqkv, 512, 0, stream>>>(hb, wqkvb, nullptr,
            qkkb, vTb, DH_, 1024, 4);
        // t = softmax(q k^T / 8) v -> tb
        attn_mfma_kernel<<<1024, 256, 0, stream>>>(qkkb, vTb, tb);
        // h_mha = t @ wob^T -> mhab
        gemm8p_kernel<2><<<gwo, 512, 0, stream>>>(tb, wob, nullptr,
            mhab, nullptr, DH_, DH_, 0);
        // h_bn = w*BN(h + h_mha) + b -> hbnb
        bn_stats_kernel<<<L_, 256, 0, stream>>>(hb, mhab, st);
        bn_apply_kernel<<<gbn, 256, 0, stream>>>(hb, mhab, st, wbn_n, bbn_n,
            hbnb, nullptr);
        // ff = relu(h_bn @ Wff0^T + bff0) @ Wff1^T + bff1 -> ffob
        gemm8p_kernel<4><<<gff0, 512, 0, stream>>>(hbnb, wff0b, bff0_n,
            ffmb, nullptr, DH_, DFF_, 1 | 2);
        gemm8p_kernel<2><<<gff1, 512, 0, stream>>>(ffmb, wff1b, bff1_n,
            ffob, nullptr, DFF_, DH_, 1);
        // h = w*BN(h_bn + ff) + b  (final layer -> fp32 d_out)
        bn_stats_kernel<<<L_, 256, 0, stream>>>(hbnb, ffob, st);
        bn_apply_kernel<<<gbn, 256, 0, stream>>>(hbnb, ffob, st, wbn_n, bbn_n,
            last ? nullptr : hb, last ? out : nullptr);
    }
}

// Round 9
// 753.596 us; speedup vs baseline: 11.1781x; 1.0300x over previous
//
#include <hip/hip_runtime.h>
#include <hip/hip_bf16.h>
#include <math.h>

// Problem constants (Encoder_24816321036413)
#define B_   16
#define L_   1024
#define BL_  16384      // B_*L_
#define DH_  512
#define DFF_ 2048
#define NL_  3
#define M_   8
#define DK_  64

typedef __attribute__((ext_vector_type(8))) short bf16x8;
typedef __attribute__((ext_vector_type(4))) float f32x4;
typedef __attribute__((ext_vector_type(4))) unsigned short us4;
typedef __attribute__((ext_vector_type(8))) unsigned short us8;

__device__ __forceinline__ unsigned short f2b(float x) {
    __hip_bfloat16 h = __float2bfloat16(x);   // RNE
    return *(unsigned short*)&h;
}
__device__ __forceinline__ float b2f(unsigned short u) {
    unsigned int v = ((unsigned int)u) << 16;
    return __builtin_bit_cast(float, v);
}

#define GLDS(g, l) __builtin_amdgcn_global_load_lds( \
        (const __attribute__((address_space(1))) unsigned int*)(const void*)(g), \
        (__attribute__((address_space(3))) unsigned int*)(void*)(l), 16, 0, 0)

// ---------------------------------------------------------------------------
// One-shot weight prep (all layers): QKV fuse, Wo repack, FF0/FF1 cvt -> bf16
#define QKV_T 2359296   // 3 layers * 3 mats * 262144
#define WO_T  786432
#define FF_T  3145728   // 3 * 2048*512
__global__ __launch_bounds__(256) void wprep_kernel(
    const float* __restrict__ Wq, const float* __restrict__ Wk,
    const float* __restrict__ Wv, const float* __restrict__ Wo,
    const float* __restrict__ Wff0, const float* __restrict__ Wff1,
    unsigned short* __restrict__ wqkvb3, unsigned short* __restrict__ wob3,
    unsigned short* __restrict__ wff0b3, unsigned short* __restrict__ wff1b3)
{
    int i4 = (blockIdx.x * 256 + threadIdx.x) * 4;
    const float* src;
    unsigned short* dst;
    if (i4 < QKV_T) {
        int n = i4 / 786432, r = i4 % 786432;
        if (r < 262144)      src = Wq + (size_t)n * 262144 + r;
        else if (r < 524288) src = Wk + (size_t)n * 262144 + r - 262144;
        else                 src = Wv + (size_t)n * 262144 + r - 524288;
        dst = wqkvb3 + i4;
    } else if (i4 < QKV_T + WO_T) {
        int i = i4 - QKV_T;
        int n = i / 262144, r = i % 262144;
        int d = r >> 9, mv = r & 511, mm = mv >> 6, vv = mv & 63;
        src = Wo + (size_t)n * 262144 + ((size_t)mm * 512 + d) * 64 + vv;
        dst = wob3 + i;
    } else if (i4 < QKV_T + WO_T + FF_T) {
        int i = i4 - QKV_T - WO_T;
        src = Wff0 + i;
        dst = wff0b3 + i;
    } else {
        int i = i4 - QKV_T - WO_T - FF_T;
        src = Wff1 + i;
        dst = wff1b3 + i;
    }
    float4 v = *(const float4*)src;
    us4 o;
    o.x = f2b(v.x); o.y = f2b(v.y); o.z = f2b(v.z); o.w = f2b(v.w);
    *(us4*)dst = o;
}

// ---------------------------------------------------------------------------
__global__ __launch_bounds__(256) void embed_kernel(
    const float* __restrict__ x, const float* __restrict__ Wh,
    const float* __restrict__ bh, unsigned short* __restrict__ hb)
{
    int idx = blockIdx.x * 256 + threadIdx.x;   // BL_*DH_/4
    int bl = idx >> 7;
    int e0 = (idx & 127) * 4;
    float x0 = x[bl * 2], x1 = x[bl * 2 + 1];
    us4 o;
    #pragma unroll
    for (int r = 0; r < 4; ++r) {
        int e = e0 + r;
        float v = fmaf(x0, Wh[e * 2], fmaf(x1, Wh[e * 2 + 1], bh[e]));
        ((unsigned short*)&o)[r] = f2b(v);
    }
    *(us4*)&hb[(size_t)bl * DH_ + e0] = o;
}

// ---------------------------------------------------------------------------
// 8-phase 256xBN bf16 GEMM-NT (HK schedule port).
// NF=4 -> BN=256 (4 phases/K-tile); NF=2 -> BN=128 (2 phases/K-tile: both
// n-frags per phase halves barrier count at equal MFMA density 16/phase).
// 512 thr = 8 waves (2M x 4N), BK=64, dbuf.  T2 swizzle both-sides.
// XCD swizzle (T1): 1D grid (nwg % 8 == 0), XCD c gets contiguous row-major
// chunk -> per-XCD L2 holds 8 A-panels + B.
// Wait ledgers (per-wave FIFO; every vmcnt precedes an s_barrier):
//  NF=4, FIFO/tile [B0,B1 | B2,B3 | A0,A2 | A1,A3]:
//   prologue vmcnt(2); end-P1 vmcnt(4) (last: 0); end-P3 vmcnt(2)
//  NF=2, FIFO/tile [B0,B1,A0 | A2,A1,A3]:
//   prologue vmcnt(2); end-P0 vmcnt(3) (last: 0); end-P1 vmcnt(2)
// flags: bit0 bias, bit1 relu, bit2 qkv-mode (col<1024 -> Cb stride cn with
//        q-cols (<512) pre-scaled by 0.125*log2e for exp2-softmax;
//        col>=1024 -> vT[(b*8+m)*64+d][l] transposed scatter).
template<int NF>
__global__ __launch_bounds__(512, 2) void gemm8p_kernel(
    const unsigned short* __restrict__ A, const unsigned short* __restrict__ Bm,
    const float* __restrict__ bias, unsigned short* __restrict__ Cb,
    unsigned short* __restrict__ vT, int K, int cn, int flags, int gx)
{
    constexpr int BN   = NF * 64;
    constexpr int SLOT = 32768 + BN * 128;       // bytes: A 32K + B (BN*128)
    __shared__ unsigned char lds[2 * SLOT];

    const int tid  = threadIdx.x;
    const int lane = tid & 63, wid = tid >> 6;
    const int wr = wid >> 2, wc = wid & 3;
    const int fr = lane & 15, fq = lane >> 4;

    // T1 XCD swizzle: contiguous chunk per XCD, bx-inner (A-panel reuse)
    const int nwg = gridDim.x;
    const int cpx = nwg >> 3;
    const int wg  = blockIdx.x;
    const int swz = (wg & 7) * cpx + (wg >> 3);
    const int by  = swz / gx;
    const int bx  = swz - by * gx;
    const int bm0 = by * 256, bn0 = bx * BN;
    const int cxor = (fr & 7) << 4;              // read-side swizzle XOR (bytes)

    const int srow  = tid >> 3;
    const int scole = ((tid & 7) ^ (srow & 7)) * 8;   // pre-swizzled source col
    const unsigned short* Ag = A  + (size_t)(bm0 + srow) * K + scole;
    const unsigned short* Bg = Bm + (size_t)(bn0 + srow) * K + scole;

    f32x4 acc[8][NF];
    #pragma unroll
    for (int i = 0; i < 8; ++i)
        #pragma unroll
        for (int j = 0; j < NF; ++j)
            acc[i][j] = (f32x4){0.f, 0.f, 0.f, 0.f};

    auto ldsA = [&](int slot, int sweep) -> void* {
        return (void*)(lds + slot * SLOT + sweep * 8192 + wid * 1024);
    };
    auto ldsB = [&](int slot, int sweep) -> void* {
        return (void*)(lds + slot * SLOT + 32768 + sweep * 8192 + wid * 1024);
    };
    auto srcA = [&](int kt, int sweep) {
        return Ag + (size_t)sweep * 64 * K + kt * 64;
    };
    auto srcB = [&](int kt, int sweep) {
        return Bg + (size_t)sweep * 64 * K + kt * 64;
    };

    const int nt = K >> 6;

    // Prologue (both NF): FIFO B..., A0,A2, A1,A3; vmcnt(2) leaves {A1,A3}
    if constexpr (NF == 4) {
        GLDS(srcB(0, 0), ldsB(0, 0)); GLDS(srcB(0, 1), ldsB(0, 1));
        GLDS(srcB(0, 2), ldsB(0, 2)); GLDS(srcB(0, 3), ldsB(0, 3));
    } else {
        GLDS(srcB(0, 0), ldsB(0, 0)); GLDS(srcB(0, 1), ldsB(0, 1));
    }
    GLDS(srcA(0, 0), ldsA(0, 0)); GLDS(srcA(0, 2), ldsA(0, 2));
    GLDS(srcA(0, 1), ldsA(0, 1)); GLDS(srcA(0, 3), ldsA(0, 3));
    asm volatile("s_waitcnt vmcnt(2)" ::: "memory");
    __builtin_amdgcn_s_barrier();

    for (int kt = 0; kt < nt; ++kt) {
        const int slot = kt & 1;
        const unsigned char* sb = lds + slot * SLOT;
        const int ns = slot ^ 1;
        const bool stg = (kt + 1 < nt);
        const int kn = kt + 1;

#define PHASE4(P)                                                              \
    {                                                                          \
        constexpr int mh = (P) >> 1, nh = (P) & 1;                             \
        bf16x8 af[4][2], bfr[2][2];                                            \
        _Pragma("unroll")                                                      \
        for (int mi = 0; mi < 4; ++mi)                                         \
            _Pragma("unroll")                                                  \
            for (int kk = 0; kk < 2; ++kk)                                     \
                af[mi][kk] = *(const bf16x8*)(sb +                             \
                    (wr * 128 + mh * 64 + mi * 16 + fr) * 128 +                \
                    ((kk * 64 + fq * 16) ^ cxor));                             \
        _Pragma("unroll")                                                      \
        for (int ni = 0; ni < 2; ++ni)                                         \
            _Pragma("unroll")                                                  \
            for (int kk = 0; kk < 2; ++kk)                                     \
                bfr[ni][kk] = *(const bf16x8*)(sb + 32768 +                    \
                    (wc * 64 + nh * 32 + ni * 16 + fr) * 128 +                 \
                    ((kk * 64 + fq * 16) ^ cxor));                             \
        if (stg) {                                                             \
            if ((P) == 0) { GLDS(srcB(kn, 0), ldsB(ns, 0));                    \
                            GLDS(srcB(kn, 1), ldsB(ns, 1)); }                  \
            if ((P) == 1) { GLDS(srcB(kn, 2), ldsB(ns, 2));                    \
                            GLDS(srcB(kn, 3), ldsB(ns, 3)); }                  \
            if ((P) == 2) { GLDS(srcA(kn, 0), ldsA(ns, 0));                    \
                            GLDS(srcA(kn, 2), ldsA(ns, 2)); }                  \
            if ((P) == 3) { GLDS(srcA(kn, 1), ldsA(ns, 1));                    \
                            GLDS(srcA(kn, 3), ldsA(ns, 3)); }                  \
        }                                                                      \
        if ((P) == 1) {                                                        \
            if (stg) asm volatile("s_waitcnt vmcnt(4)" ::: "memory");          \
            else     asm volatile("s_waitcnt vmcnt(0)" ::: "memory");          \
        }                                                                      \
        if ((P) == 3 && stg) asm volatile("s_waitcnt vmcnt(2)" ::: "memory");  \
        __builtin_amdgcn_s_barrier();                                          \
        asm volatile("s_waitcnt lgkmcnt(0)" ::: "memory");                     \
        __builtin_amdgcn_s_setprio(1);                                         \
        _Pragma("unroll")                                                      \
        for (int mi = 0; mi < 4; ++mi)                                         \
            _Pragma("unroll")                                                  \
            for (int ni = 0; ni < 2; ++ni) {                                   \
                f32x4 c = acc[mh * 4 + mi][nh * 2 + ni];                       \
                c = __builtin_amdgcn_mfma_f32_16x16x32_bf16(                   \
                        af[mi][0], bfr[ni][0], c, 0, 0, 0);                    \
                c = __builtin_amdgcn_mfma_f32_16x16x32_bf16(                   \
                        af[mi][1], bfr[ni][1], c, 0, 0, 0);                    \
                acc[mh * 4 + mi][nh * 2 + ni] = c;                             \
            }                                                                  \
        __builtin_amdgcn_s_setprio(0);                                         \
        __builtin_amdgcn_s_barrier();                                          \
    }

#define PHASE2(P)                                                              \
    {                                                                          \
        constexpr int mh = (P);                                                \
        bf16x8 af[4][2], bfr[2][2];                                            \
        _Pragma("unroll")                                                      \
        for (int mi = 0; mi < 4; ++mi)                                         \
            _Pragma("unroll")                                                  \
            for (int kk = 0; kk < 2; ++kk)                                     \
                af[mi][kk] = *(const bf16x8*)(sb +                             \
                    (wr * 128 + mh * 64 + mi * 16 + fr) * 128 +                \
                    ((kk * 64 + fq * 16) ^ cxor));                             \
        _Pragma("unroll")                                                      \
        for (int ni = 0; ni < 2; ++ni)                                         \
            _Pragma("unroll")                                                  \
            for (int kk = 0; kk < 2; ++kk)                                     \
                bfr[ni][kk] = *(const bf16x8*)(sb + 32768 +                    \
                    (wc * 32 + ni * 16 + fr) * 128 +                           \
                    ((kk * 64 + fq * 16) ^ cxor));                             \
        if (stg) {                                                             \
            if ((P) == 0) { GLDS(srcB(kn, 0), ldsB(ns, 0));                    \
                            GLDS(srcB(kn, 1), ldsB(ns, 1));                    \
                            GLDS(srcA(kn, 0), ldsA(ns, 0)); }                  \
            if ((P) == 1) { GLDS(srcA(kn, 2), ldsA(ns, 2));                    \
                            GLDS(srcA(kn, 1), ldsA(ns, 1));                    \
                            GLDS(srcA(kn, 3), ldsA(ns, 3)); }                  \
        }                                                                      \
        if ((P) == 0) {                                                        \
            if (stg) asm volatile("s_waitcnt vmcnt(3)" ::: "memory");          \
            else     asm volatile("s_waitcnt vmcnt(0)" ::: "memory");          \
        }                                                                      \
        if ((P) == 1 && stg) asm volatile("s_waitcnt vmcnt(2)" ::: "memory");  \
        __builtin_amdgcn_s_barrier();                                          \
        asm volatile("s_waitcnt lgkmcnt(0)" ::: "memory");                     \
        __builtin_amdgcn_s_setprio(1);                                         \
        _Pragma("unroll")                                                      \
        for (int mi = 0; mi < 4; ++mi)                                         \
            _Pragma("unroll")                                                  \
            for (int ni = 0; ni < 2; ++ni) {                                   \
                f32x4 c = acc[mh * 4 + mi][ni];                                \
                c = __builtin_amdgcn_mfma_f32_16x16x32_bf16(                   \
                        af[mi][0], bfr[ni][0], c, 0, 0, 0);                    \
                c = __builtin_amdgcn_mfma_f32_16x16x32_bf16(                   \
                        af[mi][1], bfr[ni][1], c, 0, 0, 0);                    \
                acc[mh * 4 + mi][ni] = c;                                      \
            }                                                                  \
        __builtin_amdgcn_s_setprio(0);                                         \
        __builtin_amdgcn_s_barrier();                                          \
    }

        if constexpr (NF == 4) {
            PHASE4(0) PHASE4(1) PHASE4(2) PHASE4(3)
        } else {
            PHASE2(0) PHASE2(1)
        }
#undef PHASE4
#undef PHASE2
    }

    // Epilogue
    float bj[NF];
    #pragma unroll
    for (int an = 0; an < NF; ++an) bj[an] = 0.f;
    if (flags & 1) {
        #pragma unroll
        for (int an = 0; an < NF; ++an)
            bj[an] = bias[bn0 + wc * NF * 16 + an * 16 + fr];
    }
    bool relu = flags & 2;
    bool qkvm = flags & 4;
    #pragma unroll
    for (int am = 0; am < 8; ++am) {
        int row0 = bm0 + wr * 128 + (am >> 2) * 64 + (am & 3) * 16 + fq * 4;
        #pragma unroll
        for (int an = 0; an < NF; ++an) {
            int col = bn0 + wc * NF * 16 + an * 16 + fr;
            float v[4];
            #pragma unroll
            for (int r = 0; r < 4; ++r) {
                v[r] = acc[am][an][r] + bj[an];
                if (relu) v[r] = fmaxf(v[r], 0.f);
            }
            if (qkvm) {
                if (col < 1024) {          // q|k row-major; q pre-scaled for exp2
                    float sc = (col < 512) ? 0.1803368801111244f : 1.0f;
                    #pragma unroll
                    for (int r = 0; r < 4; ++r)
                        Cb[(size_t)(row0 + r) * cn + col] = f2b(v[r] * sc);
                } else {                   // v -> vT[(b*8+m)*64+d][l]
                    int mm = (col - 1024) >> 6, dd = (col - 1024) & 63;
                    int bb = row0 >> 10, l0 = row0 & 1023;
                    us4 p;
                    p.x = f2b(v[0]); p.y = f2b(v[1]); p.z = f2b(v[2]); p.w = f2b(v[3]);
                    *(us4*)&vT[((size_t)(bb * 8 + mm) * 64 + dd) * 1024 + l0] = p;
                }
            } else {
                #pragma unroll
                for (int r = 0; r < 4; ++r)
                    Cb[(size_t)(row0 + r) * cn + col] = f2b(v[r]);
            }
        }
    }
}

// ---------------------------------------------------------------------------
// MFMA flash attention v2 (R8, passing): 4 waves x 32 q-rows = 128 q/WG.
// exp2f softmax (q pre-scaled by 0.125*log2e).  XCD-swizzled grid 1024.
#define KST 72
__global__ __launch_bounds__(256, 4) void attn_mfma_kernel(
    const unsigned short* __restrict__ qk, const unsigned short* __restrict__ vT,
    unsigned short* __restrict__ t)
{
    __shared__ unsigned short Ks[64 * KST];    // [key][d]
    __shared__ unsigned short Vs[64 * KST];    // [d][key]
    __shared__ unsigned short Pb[4][32 * KST]; // per-wave [q][key]

    int tid = threadIdx.x;
    int lane = tid & 63, wid = tid >> 6;
    int fr = lane & 15, fq = lane >> 4;
    int j = blockIdx.x;
    int pair = (j & 7) * 16 + (j >> 6);        // 0..127 = b*8+m
    int q0 = ((j >> 3) & 7) * 128;
    int b = pair >> 3, m = pair & 7;
    int bq = b * L_;

    size_t qbase = (size_t)(bq + q0 + wid * 32) * 1024 + m * 64;
    bf16x8 qa[2][2];
    #pragma unroll
    for (int qh = 0; qh < 2; ++qh) {
        qa[qh][0] = *(const bf16x8*)&qk[qbase + (size_t)(qh * 16 + fr) * 1024 + fq * 8];
        qa[qh][1] = *(const bf16x8*)&qk[qbase + (size_t)(qh * 16 + fr) * 1024 + 32 + fq * 8];
    }

    f32x4 oacc[2][4];
    #pragma unroll
    for (int qh = 0; qh < 2; ++qh)
        #pragma unroll
        for (int i = 0; i < 4; ++i) oacc[qh][i] = (f32x4){0.f, 0.f, 0.f, 0.f};
    float lsum[2][4] = {{0.f, 0.f, 0.f, 0.f}, {0.f, 0.f, 0.f, 0.f}};

    int srow = tid >> 3;
    int scol = (tid & 7) * 8;
    const unsigned short* kg = qk + (size_t)bq * 1024 + 512 + m * 64 + scol;
    const unsigned short* vg = vT + ((size_t)pair * 64) * 1024 + scol;
    unsigned short* pw = Pb[wid];

    uint4 k0 = *(const uint4*)&kg[(size_t)(srow) * 1024];
    uint4 k1 = *(const uint4*)&kg[(size_t)(srow + 32) * 1024];
    uint4 v0 = *(const uint4*)&vg[(size_t)(srow) * 1024];
    uint4 v1 = *(const uint4*)&vg[(size_t)(srow + 32) * 1024];

    for (int kt = 0; kt < L_ / 64; ++kt) {
        __syncthreads();
        *(uint4*)&Ks[(srow)      * KST + scol] = k0;
        *(uint4*)&Ks[(srow + 32) * KST + scol] = k1;
        *(uint4*)&Vs[(srow)      * KST + scol] = v0;
        *(uint4*)&Vs[(srow + 32) * KST + scol] = v1;
        __syncthreads();
        if (kt + 1 < L_ / 64) {
            int kb = (kt + 1) * 64;
            k0 = *(const uint4*)&kg[(size_t)(kb + srow) * 1024];
            k1 = *(const uint4*)&kg[(size_t)(kb + srow + 32) * 1024];
            v0 = *(const uint4*)&vg[(size_t)(srow) * 1024 + kb];
            v1 = *(const uint4*)&vg[(size_t)(srow + 32) * 1024 + kb];
        }

        __builtin_amdgcn_s_setprio(1);
        #pragma unroll
        for (int nk = 0; nk < 4; ++nk) {
            bf16x8 kf0 = *(const bf16x8*)&Ks[(nk * 16 + fr) * KST + fq * 8];
            bf16x8 kf1 = *(const bf16x8*)&Ks[(nk * 16 + fr) * KST + 32 + fq * 8];
            #pragma unroll
            for (int qh = 0; qh < 2; ++qh) {
                f32x4 s = __builtin_amdgcn_mfma_f32_16x16x32_bf16(
                    qa[qh][0], kf0, (f32x4){0.f, 0.f, 0.f, 0.f}, 0, 0, 0);
                s = __builtin_amdgcn_mfma_f32_16x16x32_bf16(qa[qh][1], kf1, s, 0, 0, 0);
                #pragma unroll
                for (int r = 0; r < 4; ++r) {
                    float p = exp2f(s[r]);     // v_exp_f32, hazard-safe
                    lsum[qh][r] += p;
                    pw[(qh * 16 + fq * 4 + r) * KST + nk * 16 + fr] = f2b(p);
                }
            }
        }
        bf16x8 pa[2][2];
        #pragma unroll
        for (int qh = 0; qh < 2; ++qh) {
            pa[qh][0] = *(const bf16x8*)&pw[(qh * 16 + fr) * KST + fq * 8];
            pa[qh][1] = *(const bf16x8*)&pw[(qh * 16 + fr) * KST + 32 + fq * 8];
        }
        #pragma unroll
        for (int nt = 0; nt < 4; ++nt) {
            bf16x8 vf0 = *(const bf16x8*)&Vs[(nt * 16 + fr) * KST + fq * 8];
            bf16x8 vf1 = *(const bf16x8*)&Vs[(nt * 16 + fr) * KST + 32 + fq * 8];
            #pragma unroll
            for (int qh = 0; qh < 2; ++qh) {
                oacc[qh][nt] = __builtin_amdgcn_mfma_f32_16x16x32_bf16(
                    pa[qh][0], vf0, oacc[qh][nt], 0, 0, 0);
                oacc[qh][nt] = __builtin_amdgcn_mfma_f32_16x16x32_bf16(
                    pa[qh][1], vf1, oacc[qh][nt], 0, 0, 0);
            }
        }
        __builtin_amdgcn_s_setprio(0);
    }

    #pragma unroll
    for (int qh = 0; qh < 2; ++qh)
        #pragma unroll
        for (int r = 0; r < 4; ++r) {
            float s = lsum[qh][r];
            s += __shfl_xor(s, 1); s += __shfl_xor(s, 2);
            s += __shfl_xor(s, 4); s += __shfl_xor(s, 8);
            lsum[qh][r] = 1.f / s;
        }
    #pragma unroll
    for (int qh = 0; qh < 2; ++qh)
        #pragma unroll
        for (int r = 0; r < 4; ++r) {
            size_t orow = (size_t)(bq + q0 + wid * 32 + qh * 16 + fq * 4 + r) * DH_ + m * 64;
            #pragma unroll
            for (int nt = 0; nt < 4; ++nt)
                t[orow + nt * 16 + fr] = f2b(oacc[qh][nt][r] * lsum[qh][r]);
        }
}

// ---------------------------------------------------------------------------
__global__ __launch_bounds__(256) void bn_stats_kernel(
    const unsigned short* __restrict__ a, const unsigned short* __restrict__ b,
    float* __restrict__ stats)
{
    int l = blockIdx.x, tid = threadIdx.x;
    float s = 0.f, s2 = 0.f;
    #pragma unroll
    for (int u = tid; u < 1024; u += 256) {
        int bb = u >> 6, dg = (u & 63) * 8;
        size_t off = ((size_t)bb * L_ + l) * DH_ + dg;
        us8 va = *(const us8*)&a[off];
        us8 vb = *(const us8*)&b[off];
        #pragma unroll
        for (int j = 0; j < 8; ++j) {
            float z = b2f(va[j]) + b2f(vb[j]);
            s += z;
            s2 = fmaf(z, z, s2);
        }
    }
    #pragma unroll
    for (int off = 32; off > 0; off >>= 1) {
        s  += __shfl_down(s, off);
        s2 += __shfl_down(s2, off);
    }
    __shared__ float red[8];
    int w = tid >> 6;
    if ((tid & 63) == 0) { red[w] = s; red[4 + w] = s2; }
    __syncthreads();
    if (tid == 0) {
        float S  = red[0] + red[1] + red[2] + red[3];
        float S2 = red[4] + red[5] + red[6] + red[7];
        float mu  = S * (1.f / 8192.f);
        float var = S2 * (1.f / 8192.f) - mu * mu;
        stats[l]      = mu;
        stats[L_ + l] = rsqrtf(var + 1e-5f);
    }
}

__global__ __launch_bounds__(256) void bn_apply_kernel(
    const unsigned short* __restrict__ a, const unsigned short* __restrict__ b,
    const float* __restrict__ stats, const float* __restrict__ w,
    const float* __restrict__ bias, unsigned short* __restrict__ outb,
    float* __restrict__ outf)
{
    int idx = blockIdx.x * 256 + threadIdx.x;   // BL_*DH_/8
    int bl = idx >> 6;
    int d0 = (idx & 63) * 8;
    int l  = bl & (L_ - 1);
    float mu = stats[l], rs = stats[L_ + l];
    size_t off = (size_t)bl * DH_ + d0;
    us8 va = *(const us8*)&a[off];
    us8 vb = *(const us8*)&b[off];
    float o[8];
    #pragma unroll
    for (int j = 0; j < 8; ++j) {
        float z = b2f(va[j]) + b2f(vb[j]);
        o[j] = fmaf(w[d0 + j], (z - mu) * rs, bias[d0 + j]);
    }
    if (outb) {
        us8 ob;
        #pragma unroll
        for (int j = 0; j < 8; ++j) ob[j] = f2b(o[j]);
        *(us8*)&outb[off] = ob;
    }
    if (outf) {
        float4 o0 = {o[0], o[1], o[2], o[3]};
        float4 o1 = {o[4], o[5], o[6], o[7]};
        *(float4*)&outf[off]     = o0;
        *(float4*)&outf[off + 4] = o1;
    }
}

// ---------------------------------------------------------------------------
extern "C" void kernel_launch(void* const* d_in, const int* in_sizes, int n_in,
                              void* d_out, int out_size, void* d_ws, size_t ws_size,
                              hipStream_t stream)
{
    const float* x    = (const float*)d_in[0];
    const float* Wh   = (const float*)d_in[1];
    const float* bh   = (const float*)d_in[2];
    const float* Wq   = (const float*)d_in[3];
    const float* Wk   = (const float*)d_in[4];
    const float* Wv   = (const float*)d_in[5];
    const float* Wo   = (const float*)d_in[6];
    const float* wbn  = (const float*)d_in[7];
    const float* bbn  = (const float*)d_in[8];
    const float* Wff0 = (const float*)d_in[9];
    const float* bff0 = (const float*)d_in[10];
    const float* Wff1 = (const float*)d_in[11];
    const float* bff1 = (const float*)d_in[12];
    float* out = (float*)d_out;

    // Workspace (~146 MB), all activations bf16 (layout as R5-R8)
    float* st = (float*)d_ws;
    unsigned short* hb    = (unsigned short*)(st + 2048);
    unsigned short* qkkb  = hb + (size_t)BL_ * DH_;
    unsigned short* vTb   = qkkb + (size_t)BL_ * 1024;
    unsigned short* tb    = vTb + (size_t)BL_ * DH_;
    unsigned short* mhab  = tb + (size_t)BL_ * DH_;
    unsigned short* hbnb  = mhab + (size_t)BL_ * DH_;
    unsigned short* ffob  = hbnb + (size_t)BL_ * DH_;
    unsigned short* wqkvb3 = ffob + (size_t)BL_ * DH_;
    unsigned short* wob3   = wqkvb3 + QKV_T;
    unsigned short* wff0b3 = wob3 + WO_T;
    unsigned short* wff1b3 = wff0b3 + FF_T;
    unsigned short* ffmb  = qkkb;    // alias (qkkb+vTb+tb = 64MB, dead at FF)

    wprep_kernel<<<(QKV_T + WO_T + 2 * FF_T) / 1024, 256, 0, stream>>>(
        Wq, Wk, Wv, Wo, Wff0, Wff1, wqkvb3, wob3, wff0b3, wff1b3);
    embed_kernel<<<BL_ * DH_ / 4 / 256, 256, 0, stream>>>(x, Wh, bh, hb);

    // 1D grids (all % 8 == 0 for bijective XCD swizzle): gx passed explicitly
    const int GQKV = 12 * 64;   // NF=2, gx=12
    const int GWO  = 4 * 64;    // NF=2, gx=4
    const int GFF0 = 8 * 64;    // NF=4, gx=8
    const int GFF1 = 4 * 64;    // NF=2, gx=4
    int gbn = BL_ * DH_ / 8 / 256;

    for (int n = 0; n < NL_; ++n) {
        const unsigned short* wqkvb = wqkvb3 + (size_t)n * 786432;
        const unsigned short* wob   = wob3   + (size_t)n * 262144;
        const unsigned short* wff0b = wff0b3 + (size_t)n * 1048576;
        const unsigned short* wff1b = wff1b3 + (size_t)n * 1048576;
        const float* wbn_n  = wbn  + (size_t)n * DH_;
        const float* bbn_n  = bbn  + (size_t)n * DH_;
        const float* bff0_n = bff0 + (size_t)n * DFF_;
        const float* bff1_n = bff1 + (size_t)n * DH_;
        bool last = (n == NL_ - 1);

        // qkv: q|k -> qkkb [BL][1024] (q pre-scaled), v -> vTb transposed
        gemm8p_kernel<2><<<GQKV, 512, 0, stream>>>(hb, wqkvb, nullptr,
            qkkb, vTb, DH_, 1024, 4, 12);
        // t = softmax(q k^T / 8) v -> tb
        attn_mfma_kernel<<<1024, 256, 0, stream>>>(qkkb, vTb, tb);
        // h_mha = t @ wob^T -> mhab
        gemm8p_kernel<2><<<GWO, 512, 0, stream>>>(tb, wob, nullptr,
            mhab, nullptr, DH_, DH_, 0, 4);
        // h_bn = w*BN(h + h_mha) + b -> hbnb
        bn_stats_kernel<<<L_, 256, 0, stream>>>(hb, mhab, st);
        bn_apply_kernel<<<gbn, 256, 0, stream>>>(hb, mhab, st, wbn_n, bbn_n,
            hbnb, nullptr);
        // ff = relu(h_bn @ Wff0^T + bff0) @ Wff1^T + bff1 -> ffob
        gemm8p_kernel<4><<<GFF0, 512, 0, stream>>>(hbnb, wff0b, bff0_n,
            ffmb, nullptr, DH_, DFF_, 1 | 2, 8);
        gemm8p_kernel<2><<<GFF1, 512, 0, stream>>>(ffmb, wff1b, bff1_n,
            ffob, nullptr, DFF_, DH_, 1, 4);
        // h = w*BN(h_bn + ff) + b  (final layer -> fp32 d_out)
        bn_stats_kernel<<<L_, 256, 0, stream>>>(hbnb, ffob, st);
        bn_apply_kernel<<<gbn, 256, 0, stream>>>(hbnb, ffob, st, wbn_n, bbn_n,
            last ? nullptr : hb, last ? out : nullptr);
    }
}

// Round 10
// 677.743 us; speedup vs baseline: 12.4292x; 1.1119x over previous
//
#include <hip/hip_runtime.h>
#include <hip/hip_bf16.h>
#include <math.h>

// Problem constants (Encoder_24816321036413)
#define B_   16
#define L_   1024
#define BL_  16384      // B_*L_
#define DH_  512
#define DFF_ 2048
#define NL_  3
#define M_   8
#define DK_  64

typedef __attribute__((ext_vector_type(8))) short bf16x8;
typedef __attribute__((ext_vector_type(4))) float f32x4;
typedef __attribute__((ext_vector_type(4))) unsigned short us4;
typedef __attribute__((ext_vector_type(8))) unsigned short us8;

__device__ __forceinline__ unsigned short f2b(float x) {
    __hip_bfloat16 h = __float2bfloat16(x);   // RNE
    return *(unsigned short*)&h;
}
__device__ __forceinline__ float b2f(unsigned short u) {
    unsigned int v = ((unsigned int)u) << 16;
    return __builtin_bit_cast(float, v);
}

#define GLDS(g, l) __builtin_amdgcn_global_load_lds( \
        (const __attribute__((address_space(1))) unsigned int*)(const void*)(g), \
        (__attribute__((address_space(3))) unsigned int*)(void*)(l), 16, 0, 0)

// ---------------------------------------------------------------------------
// One-shot weight prep (all layers): QKV fuse, Wo repack, FF0/FF1 cvt -> bf16
#define QKV_T 2359296   // 3 layers * 3 mats * 262144
#define WO_T  786432
#define FF_T  3145728   // 3 * 2048*512
__global__ __launch_bounds__(256) void wprep_kernel(
    const float* __restrict__ Wq, const float* __restrict__ Wk,
    const float* __restrict__ Wv, const float* __restrict__ Wo,
    const float* __restrict__ Wff0, const float* __restrict__ Wff1,
    unsigned short* __restrict__ wqkvb3, unsigned short* __restrict__ wob3,
    unsigned short* __restrict__ wff0b3, unsigned short* __restrict__ wff1b3)
{
    int i4 = (blockIdx.x * 256 + threadIdx.x) * 4;
    const float* src;
    unsigned short* dst;
    if (i4 < QKV_T) {
        int n = i4 / 786432, r = i4 % 786432;
        if (r < 262144)      src = Wq + (size_t)n * 262144 + r;
        else if (r < 524288) src = Wk + (size_t)n * 262144 + r - 262144;
        else                 src = Wv + (size_t)n * 262144 + r - 524288;
        dst = wqkvb3 + i4;
    } else if (i4 < QKV_T + WO_T) {
        int i = i4 - QKV_T;
        int n = i / 262144, r = i % 262144;
        int d = r >> 9, mv = r & 511, mm = mv >> 6, vv = mv & 63;
        src = Wo + (size_t)n * 262144 + ((size_t)mm * 512 + d) * 64 + vv;
        dst = wob3 + i;
    } else if (i4 < QKV_T + WO_T + FF_T) {
        int i = i4 - QKV_T - WO_T;
        src = Wff0 + i;
        dst = wff0b3 + i;
    } else {
        int i = i4 - QKV_T - WO_T - FF_T;
        src = Wff1 + i;
        dst = wff1b3 + i;
    }
    float4 v = *(const float4*)src;
    us4 o;
    o.x = f2b(v.x); o.y = f2b(v.y); o.z = f2b(v.z); o.w = f2b(v.w);
    *(us4*)dst = o;
}

// ---------------------------------------------------------------------------
__global__ __launch_bounds__(256) void embed_kernel(
    const float* __restrict__ x, const float* __restrict__ Wh,
    const float* __restrict__ bh, unsigned short* __restrict__ hb)
{
    int idx = blockIdx.x * 256 + threadIdx.x;   // BL_*DH_/4
    int bl = idx >> 7;
    int e0 = (idx & 127) * 4;
    float x0 = x[bl * 2], x1 = x[bl * 2 + 1];
    us4 o;
    #pragma unroll
    for (int r = 0; r < 4; ++r) {
        int e = e0 + r;
        float v = fmaf(x0, Wh[e * 2], fmaf(x1, Wh[e * 2 + 1], bh[e]));
        ((unsigned short*)&o)[r] = f2b(v);
    }
    *(us4*)&hb[(size_t)bl * DH_ + e0] = o;
}

// ---------------------------------------------------------------------------
// 2-WG/CU bf16 GEMM-NT: C[M x N] = A[M x K] * B[N x K]^T.
// BM=BN=128, BK=64; 512 thr = 8 waves (2M x 4N), per-wave 64x32 output.
// LDS = 2 slots x 32 KB = 64 KB -> 2 WGs/CU (cross-WG latency hiding replaces
// intra-tile phase barriers; ONE barrier per K-tile).  ds_reads are plain C++
// loads (compiler emits precise lgkmcnt); GLDS for tile k+1 issues early in
// tile k (~full tile of slack) so the tile-end vmcnt(0) drain is stall-free.
// T2 swizzle both-sides (linear GLDS dest + pre-swizzled source col + XOR on
// read).  T1 XCD swizzle on 1D grid (nwg % 8 == 0).
// flags: bit0 bias, bit1 relu, bit2 qkv-mode (col<1024 -> Cb stride cn with
//        q-cols (<512) pre-scaled by 0.125*log2e for exp2-softmax;
//        col>=1024 -> vT[(b*8+m)*64+d][l] transposed scatter).
__global__ __launch_bounds__(512, 4) void gemm2w_kernel(
    const unsigned short* __restrict__ A, const unsigned short* __restrict__ Bm,
    const float* __restrict__ bias, unsigned short* __restrict__ Cb,
    unsigned short* __restrict__ vT, int K, int cn, int flags, int gx)
{
    constexpr int SLOT = 32768;                  // A 16K + B 16K
    __shared__ unsigned char lds[2 * SLOT];

    const int tid  = threadIdx.x;
    const int lane = tid & 63, wid = tid >> 6;
    const int wr = wid >> 2, wc = wid & 3;       // 2M x 4N waves
    const int fr = lane & 15, fq = lane >> 4;

    const int nwg = gridDim.x;
    const int cpx = nwg >> 3;
    const int wg  = blockIdx.x;
    const int swz = (wg & 7) * cpx + (wg >> 3);
    const int by  = swz / gx;
    const int bx  = swz - by * gx;
    const int bm0 = by * 128, bn0 = bx * 128;
    const int cxor = (fr & 7) << 4;              // read-side swizzle XOR (bytes)

    const int srow  = tid >> 3;                  // 0..63
    const int scole = ((tid & 7) ^ (srow & 7)) * 8;   // pre-swizzled source col
    const unsigned short* Ag = A  + (size_t)(bm0 + srow) * K + scole;
    const unsigned short* Bg = Bm + (size_t)(bn0 + srow) * K + scole;

    f32x4 acc[4][2];
    #pragma unroll
    for (int i = 0; i < 4; ++i)
        #pragma unroll
        for (int j = 0; j < 2; ++j)
            acc[i][j] = (f32x4){0.f, 0.f, 0.f, 0.f};

    auto ldsA = [&](int slot, int sweep) -> void* {
        return (void*)(lds + slot * SLOT + sweep * 8192 + wid * 1024);
    };
    auto ldsB = [&](int slot, int sweep) -> void* {
        return (void*)(lds + slot * SLOT + 16384 + sweep * 8192 + wid * 1024);
    };
    auto srcA = [&](int kt, int sweep) {
        return Ag + (size_t)sweep * 64 * K + kt * 64;
    };
    auto srcB = [&](int kt, int sweep) {
        return Bg + (size_t)sweep * 64 * K + kt * 64;
    };

    const int nt = K >> 6;

    // Prologue: stage tile 0 -> slot 0
    GLDS(srcB(0, 0), ldsB(0, 0)); GLDS(srcB(0, 1), ldsB(0, 1));
    GLDS(srcA(0, 0), ldsA(0, 0)); GLDS(srcA(0, 1), ldsA(0, 1));
    asm volatile("s_waitcnt vmcnt(0)" ::: "memory");
    __builtin_amdgcn_s_barrier();

    for (int kt = 0; kt < nt; ++kt) {
        const int slot = kt & 1;
        const unsigned char* sb = lds + slot * SLOT;
        const int ns = slot ^ 1;
        const bool stg = (kt + 1 < nt);
        const int kn = kt + 1;

        // B-frags: read once per tile, reused across both m-halves
        bf16x8 bfr[2][2], af[2][2];
        #pragma unroll
        for (int ni = 0; ni < 2; ++ni)
            #pragma unroll
            for (int kk = 0; kk < 2; ++kk)
                bfr[ni][kk] = *(const bf16x8*)(sb + 16384 +
                    (wc * 32 + ni * 16 + fr) * 128 + ((kk * 64 + fq * 16) ^ cxor));
        #pragma unroll
        for (int mi = 0; mi < 2; ++mi)
            #pragma unroll
            for (int kk = 0; kk < 2; ++kk)
                af[mi][kk] = *(const bf16x8*)(sb +
                    (wr * 64 + mi * 16 + fr) * 128 + ((kk * 64 + fq * 16) ^ cxor));
        if (stg) {   // early issue: ~full tile of latency slack before vmcnt(0)
            GLDS(srcB(kn, 0), ldsB(ns, 0)); GLDS(srcB(kn, 1), ldsB(ns, 1));
            GLDS(srcA(kn, 0), ldsA(ns, 0)); GLDS(srcA(kn, 1), ldsA(ns, 1));
        }
        #pragma unroll
        for (int mi = 0; mi < 2; ++mi)
            #pragma unroll
            for (int ni = 0; ni < 2; ++ni) {
                f32x4 c = acc[mi][ni];
                c = __builtin_amdgcn_mfma_f32_16x16x32_bf16(af[mi][0], bfr[ni][0], c, 0, 0, 0);
                c = __builtin_amdgcn_mfma_f32_16x16x32_bf16(af[mi][1], bfr[ni][1], c, 0, 0, 0);
                acc[mi][ni] = c;
            }
        // m-half 1
        #pragma unroll
        for (int mi = 0; mi < 2; ++mi)
            #pragma unroll
            for (int kk = 0; kk < 2; ++kk)
                af[mi][kk] = *(const bf16x8*)(sb +
                    (wr * 64 + 32 + mi * 16 + fr) * 128 + ((kk * 64 + fq * 16) ^ cxor));
        #pragma unroll
        for (int mi = 0; mi < 2; ++mi)
            #pragma unroll
            for (int ni = 0; ni < 2; ++ni) {
                f32x4 c = acc[2 + mi][ni];
                c = __builtin_amdgcn_mfma_f32_16x16x32_bf16(af[mi][0], bfr[ni][0], c, 0, 0, 0);
                c = __builtin_amdgcn_mfma_f32_16x16x32_bf16(af[mi][1], bfr[ni][1], c, 0, 0, 0);
                acc[2 + mi][ni] = c;
            }
        if (stg) asm volatile("s_waitcnt vmcnt(0)" ::: "memory");
        __builtin_amdgcn_s_barrier();
    }

    // Epilogue
    float bj[2] = {0.f, 0.f};
    if (flags & 1) {
        #pragma unroll
        for (int ni = 0; ni < 2; ++ni)
            bj[ni] = bias[bn0 + wc * 32 + ni * 16 + fr];
    }
    bool relu = flags & 2;
    bool qkvm = flags & 4;
    #pragma unroll
    for (int am = 0; am < 4; ++am) {
        int row0 = bm0 + wr * 64 + (am >> 1) * 32 + (am & 1) * 16 + fq * 4;
        #pragma unroll
        for (int an = 0; an < 2; ++an) {
            int col = bn0 + wc * 32 + an * 16 + fr;
            float v[4];
            #pragma unroll
            for (int r = 0; r < 4; ++r) {
                v[r] = acc[am][an][r] + bj[an];
                if (relu) v[r] = fmaxf(v[r], 0.f);
            }
            if (qkvm) {
                if (col < 1024) {          // q|k row-major; q pre-scaled for exp2
                    float sc = (col < 512) ? 0.1803368801111244f : 1.0f;
                    #pragma unroll
                    for (int r = 0; r < 4; ++r)
                        Cb[(size_t)(row0 + r) * cn + col] = f2b(v[r] * sc);
                } else {                   // v -> vT[(b*8+m)*64+d][l]
                    int mm = (col - 1024) >> 6, dd = (col - 1024) & 63;
                    int bb = row0 >> 10, l0 = row0 & 1023;
                    us4 p;
                    p.x = f2b(v[0]); p.y = f2b(v[1]); p.z = f2b(v[2]); p.w = f2b(v[3]);
                    *(us4*)&vT[((size_t)(bb * 8 + mm) * 64 + dd) * 1024 + l0] = p;
                }
            } else {
                #pragma unroll
                for (int r = 0; r < 4; ++r)
                    Cb[(size_t)(row0 + r) * cn + col] = f2b(v[r]);
            }
        }
    }
}

// ---------------------------------------------------------------------------
// MFMA flash attention v2 (R8/R9, passing): 4 waves x 32 q-rows = 128 q/WG.
// exp2f softmax (q pre-scaled by 0.125*log2e).  XCD-swizzled grid 1024.
#define KST 72
__global__ __launch_bounds__(256, 4) void attn_mfma_kernel(
    const unsigned short* __restrict__ qk, const unsigned short* __restrict__ vT,
    unsigned short* __restrict__ t)
{
    __shared__ unsigned short Ks[64 * KST];    // [key][d]
    __shared__ unsigned short Vs[64 * KST];    // [d][key]
    __shared__ unsigned short Pb[4][32 * KST]; // per-wave [q][key]

    int tid = threadIdx.x;
    int lane = tid & 63, wid = tid >> 6;
    int fr = lane & 15, fq = lane >> 4;
    int j = blockIdx.x;
    int pair = (j & 7) * 16 + (j >> 6);        // 0..127 = b*8+m
    int q0 = ((j >> 3) & 7) * 128;
    int b = pair >> 3, m = pair & 7;
    int bq = b * L_;

    size_t qbase = (size_t)(bq + q0 + wid * 32) * 1024 + m * 64;
    bf16x8 qa[2][2];
    #pragma unroll
    for (int qh = 0; qh < 2; ++qh) {
        qa[qh][0] = *(const bf16x8*)&qk[qbase + (size_t)(qh * 16 + fr) * 1024 + fq * 8];
        qa[qh][1] = *(const bf16x8*)&qk[qbase + (size_t)(qh * 16 + fr) * 1024 + 32 + fq * 8];
    }

    f32x4 oacc[2][4];
    #pragma unroll
    for (int qh = 0; qh < 2; ++qh)
        #pragma unroll
        for (int i = 0; i < 4; ++i) oacc[qh][i] = (f32x4){0.f, 0.f, 0.f, 0.f};
    float lsum[2][4] = {{0.f, 0.f, 0.f, 0.f}, {0.f, 0.f, 0.f, 0.f}};

    int srow = tid >> 3;
    int scol = (tid & 7) * 8;
    const unsigned short* kg = qk + (size_t)bq * 1024 + 512 + m * 64 + scol;
    const unsigned short* vg = vT + ((size_t)pair * 64) * 1024 + scol;
    unsigned short* pw = Pb[wid];

    uint4 k0 = *(const uint4*)&kg[(size_t)(srow) * 1024];
    uint4 k1 = *(const uint4*)&kg[(size_t)(srow + 32) * 1024];
    uint4 v0 = *(const uint4*)&vg[(size_t)(srow) * 1024];
    uint4 v1 = *(const uint4*)&vg[(size_t)(srow + 32) * 1024];

    for (int kt = 0; kt < L_ / 64; ++kt) {
        __syncthreads();
        *(uint4*)&Ks[(srow)      * KST + scol] = k0;
        *(uint4*)&Ks[(srow + 32) * KST + scol] = k1;
        *(uint4*)&Vs[(srow)      * KST + scol] = v0;
        *(uint4*)&Vs[(srow + 32) * KST + scol] = v1;
        __syncthreads();
        if (kt + 1 < L_ / 64) {
            int kb = (kt + 1) * 64;
            k0 = *(const uint4*)&kg[(size_t)(kb + srow) * 1024];
            k1 = *(const uint4*)&kg[(size_t)(kb + srow + 32) * 1024];
            v0 = *(const uint4*)&vg[(size_t)(srow) * 1024 + kb];
            v1 = *(const uint4*)&vg[(size_t)(srow + 32) * 1024 + kb];
        }

        __builtin_amdgcn_s_setprio(1);
        #pragma unroll
        for (int nk = 0; nk < 4; ++nk) {
            bf16x8 kf0 = *(const bf16x8*)&Ks[(nk * 16 + fr) * KST + fq * 8];
            bf16x8 kf1 = *(const bf16x8*)&Ks[(nk * 16 + fr) * KST + 32 + fq * 8];
            #pragma unroll
            for (int qh = 0; qh < 2; ++qh) {
                f32x4 s = __builtin_amdgcn_mfma_f32_16x16x32_bf16(
                    qa[qh][0], kf0, (f32x4){0.f, 0.f, 0.f, 0.f}, 0, 0, 0);
                s = __builtin_amdgcn_mfma_f32_16x16x32_bf16(qa[qh][1], kf1, s, 0, 0, 0);
                #pragma unroll
                for (int r = 0; r < 4; ++r) {
                    float p = exp2f(s[r]);     // v_exp_f32, hazard-safe
                    lsum[qh][r] += p;
                    pw[(qh * 16 + fq * 4 + r) * KST + nk * 16 + fr] = f2b(p);
                }
            }
        }
        bf16x8 pa[2][2];
        #pragma unroll
        for (int qh = 0; qh < 2; ++qh) {
            pa[qh][0] = *(const bf16x8*)&pw[(qh * 16 + fr) * KST + fq * 8];
            pa[qh][1] = *(const bf16x8*)&pw[(qh * 16 + fr) * KST + 32 + fq * 8];
        }
        #pragma unroll
        for (int nt = 0; nt < 4; ++nt) {
            bf16x8 vf0 = *(const bf16x8*)&Vs[(nt * 16 + fr) * KST + fq * 8];
            bf16x8 vf1 = *(const bf16x8*)&Vs[(nt * 16 + fr) * KST + 32 + fq * 8];
            #pragma unroll
            for (int qh = 0; qh < 2; ++qh) {
                oacc[qh][nt] = __builtin_amdgcn_mfma_f32_16x16x32_bf16(
                    pa[qh][0], vf0, oacc[qh][nt], 0, 0, 0);
                oacc[qh][nt] = __builtin_amdgcn_mfma_f32_16x16x32_bf16(
                    pa[qh][1], vf1, oacc[qh][nt], 0, 0, 0);
            }
        }
        __builtin_amdgcn_s_setprio(0);
    }

    #pragma unroll
    for (int qh = 0; qh < 2; ++qh)
        #pragma unroll
        for (int r = 0; r < 4; ++r) {
            float s = lsum[qh][r];
            s += __shfl_xor(s, 1); s += __shfl_xor(s, 2);
            s += __shfl_xor(s, 4); s += __shfl_xor(s, 8);
            lsum[qh][r] = 1.f / s;
        }
    #pragma unroll
    for (int qh = 0; qh < 2; ++qh)
        #pragma unroll
        for (int r = 0; r < 4; ++r) {
            size_t orow = (size_t)(bq + q0 + wid * 32 + qh * 16 + fq * 4 + r) * DH_ + m * 64;
            #pragma unroll
            for (int nt = 0; nt < 4; ++nt)
                t[orow + nt * 16 + fr] = f2b(oacc[qh][nt][r] * lsum[qh][r]);
        }
}

// ---------------------------------------------------------------------------
__global__ __launch_bounds__(256) void bn_stats_kernel(
    const unsigned short* __restrict__ a, const unsigned short* __restrict__ b,
    float* __restrict__ stats)
{
    int l = blockIdx.x, tid = threadIdx.x;
    float s = 0.f, s2 = 0.f;
    #pragma unroll
    for (int u = tid; u < 1024; u += 256) {
        int bb = u >> 6, dg = (u & 63) * 8;
        size_t off = ((size_t)bb * L_ + l) * DH_ + dg;
        us8 va = *(const us8*)&a[off];
        us8 vb = *(const us8*)&b[off];
        #pragma unroll
        for (int j = 0; j < 8; ++j) {
            float z = b2f(va[j]) + b2f(vb[j]);
            s += z;
            s2 = fmaf(z, z, s2);
        }
    }
    #pragma unroll
    for (int off = 32; off > 0; off >>= 1) {
        s  += __shfl_down(s, off);
        s2 += __shfl_down(s2, off);
    }
    __shared__ float red[8];
    int w = tid >> 6;
    if ((tid & 63) == 0) { red[w] = s; red[4 + w] = s2; }
    __syncthreads();
    if (tid == 0) {
        float S  = red[0] + red[1] + red[2] + red[3];
        float S2 = red[4] + red[5] + red[6] + red[7];
        float mu  = S * (1.f / 8192.f);
        float var = S2 * (1.f / 8192.f) - mu * mu;
        stats[l]      = mu;
        stats[L_ + l] = rsqrtf(var + 1e-5f);
    }
}

__global__ __launch_bounds__(256) void bn_apply_kernel(
    const unsigned short* __restrict__ a, const unsigned short* __restrict__ b,
    const float* __restrict__ stats, const float* __restrict__ w,
    const float* __restrict__ bias, unsigned short* __restrict__ outb,
    float* __restrict__ outf)
{
    int idx = blockIdx.x * 256 + threadIdx.x;   // BL_*DH_/8
    int bl = idx >> 6;
    int d0 = (idx & 63) * 8;
    int l  = bl & (L_ - 1);
    float mu = stats[l], rs = stats[L_ + l];
    size_t off = (size_t)bl * DH_ + d0;
    us8 va = *(const us8*)&a[off];
    us8 vb = *(const us8*)&b[off];
    float o[8];
    #pragma unroll
    for (int j = 0; j < 8; ++j) {
        float z = b2f(va[j]) + b2f(vb[j]);
        o[j] = fmaf(w[d0 + j], (z - mu) * rs, bias[d0 + j]);
    }
    if (outb) {
        us8 ob;
        #pragma unroll
        for (int j = 0; j < 8; ++j) ob[j] = f2b(o[j]);
        *(us8*)&outb[off] = ob;
    }
    if (outf) {
        float4 o0 = {o[0], o[1], o[2], o[3]};
        float4 o1 = {o[4], o[5], o[6], o[7]};
        *(float4*)&outf[off]     = o0;
        *(float4*)&outf[off + 4] = o1;
    }
}

// ---------------------------------------------------------------------------
extern "C" void kernel_launch(void* const* d_in, const int* in_sizes, int n_in,
                              void* d_out, int out_size, void* d_ws, size_t ws_size,
                              hipStream_t stream)
{
    const float* x    = (const float*)d_in[0];
    const float* Wh   = (const float*)d_in[1];
    const float* bh   = (const float*)d_in[2];
    const float* Wq   = (const float*)d_in[3];
    const float* Wk   = (const float*)d_in[4];
    const float* Wv   = (const float*)d_in[5];
    const float* Wo   = (const float*)d_in[6];
    const float* wbn  = (const float*)d_in[7];
    const float* bbn  = (const float*)d_in[8];
    const float* Wff0 = (const float*)d_in[9];
    const float* bff0 = (const float*)d_in[10];
    const float* Wff1 = (const float*)d_in[11];
    const float* bff1 = (const float*)d_in[12];
    float* out = (float*)d_out;

    // Workspace (~146 MB), all activations bf16 (layout as R5-R9)
    float* st = (float*)d_ws;
    unsigned short* hb    = (unsigned short*)(st + 2048);
    unsigned short* qkkb  = hb + (size_t)BL_ * DH_;
    unsigned short* vTb   = qkkb + (size_t)BL_ * 1024;
    unsigned short* tb    = vTb + (size_t)BL_ * DH_;
    unsigned short* mhab  = tb + (size_t)BL_ * DH_;
    unsigned short* hbnb  = mhab + (size_t)BL_ * DH_;
    unsigned short* ffob  = hbnb + (size_t)BL_ * DH_;
    unsigned short* wqkvb3 = ffob + (size_t)BL_ * DH_;
    unsigned short* wob3   = wqkvb3 + QKV_T;
    unsigned short* wff0b3 = wob3 + WO_T;
    unsigned short* wff1b3 = wff0b3 + FF_T;
    unsigned short* ffmb  = qkkb;    // alias (qkkb+vTb+tb = 64MB, dead at FF)

    wprep_kernel<<<(QKV_T + WO_T + 2 * FF_T) / 1024, 256, 0, stream>>>(
        Wq, Wk, Wv, Wo, Wff0, Wff1, wqkvb3, wob3, wff0b3, wff1b3);
    embed_kernel<<<BL_ * DH_ / 4 / 256, 256, 0, stream>>>(x, Wh, bh, hb);

    // 1D grids (%8 for XCD swizzle); BM=128 doubles grids -> 2 WG/CU rounds
    const int GQKV = 12 * 128;   // gx=12 -> 1536 WGs = 3 rounds
    const int GWO  = 4 * 128;    // gx=4  -> 512  = 1 round
    const int GFF0 = 16 * 128;   // gx=16 -> 2048 = 4 rounds
    const int GFF1 = 4 * 128;    // gx=4  -> 512  = 1 round
    int gbn = BL_ * DH_ / 8 / 256;

    for (int n = 0; n < NL_; ++n) {
        const unsigned short* wqkvb = wqkvb3 + (size_t)n * 786432;
        const unsigned short* wob   = wob3   + (size_t)n * 262144;
        const unsigned short* wff0b = wff0b3 + (size_t)n * 1048576;
        const unsigned short* wff1b = wff1b3 + (size_t)n * 1048576;
        const float* wbn_n  = wbn  + (size_t)n * DH_;
        const float* bbn_n  = bbn  + (size_t)n * DH_;
        const float* bff0_n = bff0 + (size_t)n * DFF_;
        const float* bff1_n = bff1 + (size_t)n * DH_;
        bool last = (n == NL_ - 1);

        // qkv: q|k -> qkkb [BL][1024] (q pre-scaled), v -> vTb transposed
        gemm2w_kernel<<<GQKV, 512, 0, stream>>>(hb, wqkvb, nullptr,
            qkkb, vTb, DH_, 1024, 4, 12);
        // t = softmax(q k^T / 8) v -> tb
        attn_mfma_kernel<<<1024, 256, 0, stream>>>(qkkb, vTb, tb);
        // h_mha = t @ wob^T -> mhab
        gemm2w_kernel<<<GWO, 512, 0, stream>>>(tb, wob, nullptr,
            mhab, nullptr, DH_, DH_, 0, 4);
        // h_bn = w*BN(h + h_mha) + b -> hbnb
        bn_stats_kernel<<<L_, 256, 0, stream>>>(hb, mhab, st);
        bn_apply_kernel<<<gbn, 256, 0, stream>>>(hb, mhab, st, wbn_n, bbn_n,
            hbnb, nullptr);
        // ff = relu(h_bn @ Wff0^T + bff0) @ Wff1^T + bff1 -> ffob
        gemm2w_kernel<<<GFF0, 512, 0, stream>>>(hbnb, wff0b, bff0_n,
            ffmb, nullptr, DH_, DFF_, 1 | 2, 16);
        gemm2w_kernel<<<GFF1, 512, 0, stream>>>(ffmb, wff1b, bff1_n,
            ffob, nullptr, DFF_, DH_, 1, 4);
        // h = w*BN(h_bn + ff) + b  (final layer -> fp32 d_out)
        bn_stats_kernel<<<L_, 256, 0, stream>>>(hbnb, ffob, st);
        bn_apply_kernel<<<gbn, 256, 0, stream>>>(hbnb, ffob, st, wbn_n, bbn_n,
            last ? nullptr : hb, last ? out : nullptr);
    }
}